// Round 1
// baseline (1577.451 us; speedup 1.0000x reference)
//
#include <hip/hip_runtime.h>

#define N_USERC 50000
#define N_ITEMC 50000
#define NTOT    100000
#define NNZC    3200000
#define EMBC    64
#define BATCHC  4096
#define NSLOT   (3*BATCHC)

// ---------------- init: ego = concat(user_emb, item_emb) ----------------
__global__ void k_init_ego(const float4* __restrict__ ue, const float4* __restrict__ ie,
                           float4* __restrict__ ego) {
    long i = (long)blockIdx.x * blockDim.x + threadIdx.x;          // float4 index
    const long nu4 = (long)N_USERC * EMBC / 4;                      // 800000
    const long tot4 = (long)NTOT * EMBC / 4;                        // 1600000
    if (i < tot4) ego[i] = (i < nu4) ? ue[i] : ie[i - nu4];
}

// ---------------- CSR build ----------------
__global__ void k_zero_cnt(int* cnt) {
    int i = blockIdx.x * blockDim.x + threadIdx.x;
    if (i < NTOT) cnt[i] = 0;
}

__global__ void k_hist(const int* __restrict__ row, int* __restrict__ cnt) {
    int e = blockIdx.x * blockDim.x + threadIdx.x;
    if (e < NNZC) atomicAdd(&cnt[row[e]], 1);
}

// per-block exclusive scan (256 elems/block); writes block totals
__global__ void k_scan1(const int* __restrict__ cnt, int* __restrict__ rp, int* __restrict__ bsum) {
    __shared__ int sm[256];
    int i = blockIdx.x * 256 + threadIdx.x;
    int v = (i < NTOT) ? cnt[i] : 0;
    sm[threadIdx.x] = v;
    __syncthreads();
    for (int off = 1; off < 256; off <<= 1) {
        int t = (threadIdx.x >= off) ? sm[threadIdx.x - off] : 0;
        __syncthreads();
        sm[threadIdx.x] += t;
        __syncthreads();
    }
    if (i < NTOT) rp[i] = sm[threadIdx.x] - v;   // exclusive within block
    if (threadIdx.x == 255) bsum[blockIdx.x] = sm[255];
}

// single-block exclusive scan of block sums (nb <= 512)
__global__ void k_scan2(int* bsum, int nb) {
    __shared__ int sm[512];
    int v = (threadIdx.x < nb) ? bsum[threadIdx.x] : 0;
    sm[threadIdx.x] = v;
    __syncthreads();
    for (int off = 1; off < 512; off <<= 1) {
        int t = (threadIdx.x >= off) ? sm[threadIdx.x - off] : 0;
        __syncthreads();
        sm[threadIdx.x] += t;
        __syncthreads();
    }
    if (threadIdx.x < nb) bsum[threadIdx.x] = sm[threadIdx.x] - v;  // exclusive
}

__global__ void k_scan3(int* __restrict__ rp, const int* __restrict__ bsum, int* __restrict__ cursor) {
    int i = blockIdx.x * 256 + threadIdx.x;
    if (i < NTOT) {
        int v = rp[i] + bsum[blockIdx.x];
        rp[i] = v;
        cursor[i] = v;
    }
    if (i == 0) rp[NTOT] = NNZC;
}

__global__ void k_scatter(const int* __restrict__ row, const int* __restrict__ col,
                          const float* __restrict__ val, int* __restrict__ cursor,
                          int* __restrict__ cs, float* __restrict__ vs) {
    int e = blockIdx.x * blockDim.x + threadIdx.x;
    if (e < NNZC) {
        int r = row[e];
        int p = atomicAdd(&cursor[r], 1);
        cs[p] = col[e];
        vs[p] = val[e];
    }
}

// ---------------- SpMM: one wave per row, lane = emb dim ----------------
__global__ __launch_bounds__(256) void k_spmm(const int* __restrict__ rp, const int* __restrict__ cs,
                                              const float* __restrict__ vs, const float* __restrict__ x,
                                              float* __restrict__ side) {
    int r = (blockIdx.x * blockDim.x + threadIdx.x) >> 6;   // row
    int lane = threadIdx.x & 63;
    if (r >= NTOT) return;
    int s = rp[r], e = rp[r + 1];
    float acc = 0.f;
    for (int base = s; base < e; base += 64) {
        int n = e - base; if (n > 64) n = 64;
        int c = 0; float v = 0.f;
        if (lane < n) { c = cs[base + lane]; v = vs[base + lane]; }
        for (int j = 0; j < n; j++) {
            int   cj = __shfl(c, j);
            float vj = __shfl(v, j);
            acc += vj * x[(long)cj * EMBC + lane];
        }
    }
    side[(long)r * EMBC + lane] = acc;
}

// ------------- fused: sum_emb + bi_emb + leaky_relu, in-place ego update -------------
__global__ __launch_bounds__(256) void k_layer(const float* __restrict__ side, float* __restrict__ ego,
                                               const float* __restrict__ Wgc, const float* __restrict__ bgc,
                                               const float* __restrict__ Wbi, const float* __restrict__ bbi) {
    __shared__ float sWgc[64 * 64];
    __shared__ float sWbi[64 * 64];
    __shared__ float sb[128];
    for (int i = threadIdx.x; i < 4096; i += 256) { sWgc[i] = Wgc[i]; sWbi[i] = Wbi[i]; }
    if (threadIdx.x < 128) sb[threadIdx.x] = (threadIdx.x < 64) ? bgc[threadIdx.x] : bbi[threadIdx.x - 64];
    __syncthreads();
    int r = (blockIdx.x * blockDim.x + threadIdx.x) >> 6;   // 4 rows per block, grid=25000 exact
    int lane = threadIdx.x & 63;
    float s = side[(long)r * 64 + lane];
    float e = ego[(long)r * 64 + lane];
    float m = e * s;
    float accg = sb[lane], accb = sb[64 + lane];
    #pragma unroll 8
    for (int d = 0; d < 64; d++) {
        float sv = __shfl(s, d);
        float mv = __shfl(m, d);
        accg += sv * sWgc[d * 64 + lane];
        accb += mv * sWbi[d * 64 + lane];
    }
    float xv = accg + accb;
    float o = (xv > 0.f) ? xv : 0.2f * xv;
    ego[(long)r * 64 + lane] = o;
}

// ------------- gather batch rows (optionally L2-normalized) into d_out -------------
__global__ __launch_bounds__(256) void k_gather(const float* __restrict__ ego,
                                                const int* __restrict__ users,
                                                const int* __restrict__ pos,
                                                const int* __restrict__ neg,
                                                float* __restrict__ out, int colOff, int normalize) {
    int slot = (blockIdx.x * blockDim.x + threadIdx.x) >> 6;
    int lane = threadIdx.x & 63;
    if (slot >= NSLOT) return;
    int row;
    if (slot < BATCHC)          row = users[slot];
    else if (slot < 2 * BATCHC) row = N_USERC + pos[slot - BATCHC];
    else                        row = N_USERC + neg[slot - 2 * BATCHC];
    float v = ego[(long)row * 64 + lane];
    if (normalize) {
        float ss = v * v;
        for (int off = 32; off > 0; off >>= 1) ss += __shfl_xor(ss, off);
        float nrm = fmaxf(sqrtf(ss), 1e-12f);
        v = v / nrm;
    }
    out[(long)slot * 256 + colOff + lane] = v;
}

extern "C" void kernel_launch(void* const* d_in, const int* in_sizes, int n_in,
                              void* d_out, int out_size, void* d_ws, size_t ws_size,
                              hipStream_t stream) {
    const int*   users   = (const int*)d_in[0];
    const int*   pos     = (const int*)d_in[1];
    const int*   neg     = (const int*)d_in[2];
    const int*   adj_row = (const int*)d_in[3];
    const int*   adj_col = (const int*)d_in[4];
    const float* adj_val = (const float*)d_in[5];
    const float* user_emb = (const float*)d_in[6];
    const float* item_emb = (const float*)d_in[7];
    const float* W_gc = (const float*)d_in[8];
    const float* b_gc = (const float*)d_in[9];
    const float* W_bi = (const float*)d_in[10];
    const float* b_bi = (const float*)d_in[11];
    float* out = (float*)d_out;

    // workspace carve-up (~78 MB)
    char* p = (char*)d_ws;
    float* ego  = (float*)p;               p += (size_t)NTOT * EMBC * 4;
    float* side = (float*)p;               p += (size_t)NTOT * EMBC * 4;
    int*   cs   = (int*)p;                 p += (size_t)NNZC * 4;
    float* vs   = (float*)p;               p += (size_t)NNZC * 4;
    int*   cnt  = (int*)p;                 p += (size_t)NTOT * 4;
    int*   rp   = (int*)p;                 p += (size_t)(NTOT + 1) * 4 + 60; // row_ptr (pad align)
    int*   cursor = (int*)p;               p += (size_t)NTOT * 4;
    int*   bsum = (int*)p;                 p += 2048;

    const int NB_SCAN = (NTOT + 255) / 256;   // 391

    // init ego
    k_init_ego<<<(NTOT * EMBC / 4 + 255) / 256, 256, 0, stream>>>(
        (const float4*)user_emb, (const float4*)item_emb, (float4*)ego);

    // CSR build
    k_zero_cnt<<<NB_SCAN, 256, 0, stream>>>(cnt);
    k_hist<<<NNZC / 256, 256, 0, stream>>>(adj_row, cnt);
    k_scan1<<<NB_SCAN, 256, 0, stream>>>(cnt, rp, bsum);
    k_scan2<<<1, 512, 0, stream>>>(bsum, NB_SCAN);
    k_scan3<<<NB_SCAN, 256, 0, stream>>>(rp, bsum, cursor);
    k_scatter<<<NNZC / 256, 256, 0, stream>>>(adj_row, adj_col, adj_val, cursor, cs, vs);

    // layer-0 slice of all_embs = raw ego (no normalization)
    k_gather<<<(NSLOT * 64 + 255) / 256, 256, 0, stream>>>(ego, users, pos, neg, out, 0, 0);

    for (int k = 0; k < 3; k++) {
        k_spmm<<<NTOT / 4, 256, 0, stream>>>(rp, cs, vs, ego, side);
        k_layer<<<NTOT / 4, 256, 0, stream>>>(side, ego,
            W_gc + (size_t)k * 4096, b_gc + (size_t)k * 64,
            W_bi + (size_t)k * 4096, b_bi + (size_t)k * 64);
        k_gather<<<(NSLOT * 64 + 255) / 256, 256, 0, stream>>>(ego, users, pos, neg, out, 64 * (k + 1), 1);
    }
}

// Round 2
// 1522.592 us; speedup vs baseline: 1.0360x; 1.0360x over previous
//
#include <hip/hip_runtime.h>

#define N_USERC 50000
#define N_ITEMC 50000
#define NTOT    100000
#define NNZC    3200000
#define EMBC    64
#define BATCHC  4096
#define NSLOT   (3*BATCHC)

// ---------------- init: ego = concat(user_emb, item_emb) ----------------
__global__ void k_init_ego(const float4* __restrict__ ue, const float4* __restrict__ ie,
                           float4* __restrict__ ego) {
    long i = (long)blockIdx.x * blockDim.x + threadIdx.x;          // float4 index
    const long nu4 = (long)N_USERC * EMBC / 4;                      // 800000
    const long tot4 = (long)NTOT * EMBC / 4;                        // 1600000
    if (i < tot4) ego[i] = (i < nu4) ? ue[i] : ie[i - nu4];
}

// ---------------- CSR build ----------------
__global__ void k_zero_cnt(int* cnt) {
    int i = blockIdx.x * blockDim.x + threadIdx.x;
    if (i < NTOT) cnt[i] = 0;
}

__global__ void k_hist(const int* __restrict__ row, int* __restrict__ cnt) {
    int e = blockIdx.x * blockDim.x + threadIdx.x;
    if (e < NNZC) atomicAdd(&cnt[__builtin_nontemporal_load(row + e)], 1);
}

// per-block exclusive scan (256 elems/block); writes block totals
__global__ void k_scan1(const int* __restrict__ cnt, int* __restrict__ rp, int* __restrict__ bsum) {
    __shared__ int sm[256];
    int i = blockIdx.x * 256 + threadIdx.x;
    int v = (i < NTOT) ? cnt[i] : 0;
    sm[threadIdx.x] = v;
    __syncthreads();
    for (int off = 1; off < 256; off <<= 1) {
        int t = (threadIdx.x >= off) ? sm[threadIdx.x - off] : 0;
        __syncthreads();
        sm[threadIdx.x] += t;
        __syncthreads();
    }
    if (i < NTOT) rp[i] = sm[threadIdx.x] - v;   // exclusive within block
    if (threadIdx.x == 255) bsum[blockIdx.x] = sm[255];
}

// single-block exclusive scan of block sums (nb <= 512)
__global__ void k_scan2(int* bsum, int nb) {
    __shared__ int sm[512];
    int v = (threadIdx.x < nb) ? bsum[threadIdx.x] : 0;
    sm[threadIdx.x] = v;
    __syncthreads();
    for (int off = 1; off < 512; off <<= 1) {
        int t = (threadIdx.x >= off) ? sm[threadIdx.x - off] : 0;
        __syncthreads();
        sm[threadIdx.x] += t;
        __syncthreads();
    }
    if (threadIdx.x < nb) bsum[threadIdx.x] = sm[threadIdx.x] - v;  // exclusive
}

__global__ void k_scan3(int* __restrict__ rp, const int* __restrict__ bsum, int* __restrict__ cursor) {
    int i = blockIdx.x * 256 + threadIdx.x;
    if (i < NTOT) {
        int v = rp[i] + bsum[blockIdx.x];
        rp[i] = v;
        cursor[i] = v;
    }
    if (i == 0) rp[NTOT] = NNZC;
}

// packed scatter: one 8B store per edge: low32=col, high32=val bits
__global__ void k_scatter(const int* __restrict__ row, const int* __restrict__ col,
                          const float* __restrict__ val, int* __restrict__ cursor,
                          long* __restrict__ ecv) {
    int e = blockIdx.x * blockDim.x + threadIdx.x;
    if (e < NNZC) {
        int r = __builtin_nontemporal_load(row + e);
        int c = __builtin_nontemporal_load(col + e);
        float v = __builtin_nontemporal_load(val + e);
        int p = atomicAdd(&cursor[r], 1);
        ecv[p] = ((long)__float_as_int(v) << 32) | (unsigned int)c;
    }
}

// ---------------- SpMM: one wave per row, lane = emb dim ----------------
// Edge word is wave-uniform address -> single broadcast load, no shfl.
__global__ __launch_bounds__(256) void k_spmm(const int* __restrict__ rp, const long* __restrict__ ecv,
                                              const float* __restrict__ x, float* __restrict__ side) {
    int r = (blockIdx.x * blockDim.x + threadIdx.x) >> 6;   // row
    int lane = threadIdx.x & 63;
    if (r >= NTOT) return;
    int s = rp[r], e = rp[r + 1];
    float acc = 0.f;
    int j = s;
    for (; j + 4 <= e; j += 4) {
        long p0 = __builtin_nontemporal_load(ecv + j);
        long p1 = __builtin_nontemporal_load(ecv + j + 1);
        long p2 = __builtin_nontemporal_load(ecv + j + 2);
        long p3 = __builtin_nontemporal_load(ecv + j + 3);
        float x0 = x[(long)(int)p0 * EMBC + lane];
        float x1 = x[(long)(int)p1 * EMBC + lane];
        float x2 = x[(long)(int)p2 * EMBC + lane];
        float x3 = x[(long)(int)p3 * EMBC + lane];
        acc += __int_as_float((int)(p0 >> 32)) * x0;
        acc += __int_as_float((int)(p1 >> 32)) * x1;
        acc += __int_as_float((int)(p2 >> 32)) * x2;
        acc += __int_as_float((int)(p3 >> 32)) * x3;
    }
    for (; j < e; ++j) {
        long p0 = __builtin_nontemporal_load(ecv + j);
        acc += __int_as_float((int)(p0 >> 32)) * x[(long)(int)p0 * EMBC + lane];
    }
    side[(long)r * EMBC + lane] = acc;
}

// ------------- fused: sum_emb + bi_emb + leaky_relu, in-place ego update -------------
__global__ __launch_bounds__(256) void k_layer(const float* __restrict__ side, float* __restrict__ ego,
                                               const float* __restrict__ Wgc, const float* __restrict__ bgc,
                                               const float* __restrict__ Wbi, const float* __restrict__ bbi) {
    __shared__ float sWgc[64 * 64];
    __shared__ float sWbi[64 * 64];
    __shared__ float sb[128];
    for (int i = threadIdx.x; i < 4096; i += 256) { sWgc[i] = Wgc[i]; sWbi[i] = Wbi[i]; }
    if (threadIdx.x < 128) sb[threadIdx.x] = (threadIdx.x < 64) ? bgc[threadIdx.x] : bbi[threadIdx.x - 64];
    __syncthreads();
    int r = (blockIdx.x * blockDim.x + threadIdx.x) >> 6;   // 4 rows per block, grid=25000 exact
    int lane = threadIdx.x & 63;
    float s = side[(long)r * 64 + lane];
    float e = ego[(long)r * 64 + lane];
    float m = e * s;
    float accg = sb[lane], accb = sb[64 + lane];
    #pragma unroll 8
    for (int d = 0; d < 64; d++) {
        float sv = __shfl(s, d);
        float mv = __shfl(m, d);
        accg += sv * sWgc[d * 64 + lane];
        accb += mv * sWbi[d * 64 + lane];
    }
    float xv = accg + accb;
    float o = (xv > 0.f) ? xv : 0.2f * xv;
    ego[(long)r * 64 + lane] = o;
}

// ------------- gather batch rows (optionally L2-normalized) into d_out -------------
__global__ __launch_bounds__(256) void k_gather(const float* __restrict__ ego,
                                                const int* __restrict__ users,
                                                const int* __restrict__ pos,
                                                const int* __restrict__ neg,
                                                float* __restrict__ out, int colOff, int normalize) {
    int slot = (blockIdx.x * blockDim.x + threadIdx.x) >> 6;
    int lane = threadIdx.x & 63;
    if (slot >= NSLOT) return;
    int row;
    if (slot < BATCHC)          row = users[slot];
    else if (slot < 2 * BATCHC) row = N_USERC + pos[slot - BATCHC];
    else                        row = N_USERC + neg[slot - 2 * BATCHC];
    float v = ego[(long)row * 64 + lane];
    if (normalize) {
        float ss = v * v;
        for (int off = 32; off > 0; off >>= 1) ss += __shfl_xor(ss, off);
        float nrm = fmaxf(sqrtf(ss), 1e-12f);
        v = v / nrm;
    }
    out[(long)slot * 256 + colOff + lane] = v;
}

extern "C" void kernel_launch(void* const* d_in, const int* in_sizes, int n_in,
                              void* d_out, int out_size, void* d_ws, size_t ws_size,
                              hipStream_t stream) {
    const int*   users   = (const int*)d_in[0];
    const int*   pos     = (const int*)d_in[1];
    const int*   neg     = (const int*)d_in[2];
    const int*   adj_row = (const int*)d_in[3];
    const int*   adj_col = (const int*)d_in[4];
    const float* adj_val = (const float*)d_in[5];
    const float* user_emb = (const float*)d_in[6];
    const float* item_emb = (const float*)d_in[7];
    const float* W_gc = (const float*)d_in[8];
    const float* b_gc = (const float*)d_in[9];
    const float* W_bi = (const float*)d_in[10];
    const float* b_bi = (const float*)d_in[11];
    float* out = (float*)d_out;

    // workspace carve-up (~78 MB)
    char* p = (char*)d_ws;
    float* ego  = (float*)p;               p += (size_t)NTOT * EMBC * 4;
    float* side = (float*)p;               p += (size_t)NTOT * EMBC * 4;
    long*  ecv  = (long*)p;                p += (size_t)NNZC * 8;     // packed (col,val)
    int*   cnt  = (int*)p;                 p += (size_t)NTOT * 4;
    int*   rp   = (int*)p;                 p += (size_t)(NTOT + 1) * 4 + 60; // row_ptr (pad align)
    int*   cursor = (int*)p;               p += (size_t)NTOT * 4;
    int*   bsum = (int*)p;                 p += 2048;

    const int NB_SCAN = (NTOT + 255) / 256;   // 391

    // init ego
    k_init_ego<<<(NTOT * EMBC / 4 + 255) / 256, 256, 0, stream>>>(
        (const float4*)user_emb, (const float4*)item_emb, (float4*)ego);

    // CSR build
    k_zero_cnt<<<NB_SCAN, 256, 0, stream>>>(cnt);
    k_hist<<<NNZC / 256, 256, 0, stream>>>(adj_row, cnt);
    k_scan1<<<NB_SCAN, 256, 0, stream>>>(cnt, rp, bsum);
    k_scan2<<<1, 512, 0, stream>>>(bsum, NB_SCAN);
    k_scan3<<<NB_SCAN, 256, 0, stream>>>(rp, bsum, cursor);
    k_scatter<<<NNZC / 256, 256, 0, stream>>>(adj_row, adj_col, adj_val, cursor, ecv);

    // layer-0 slice of all_embs = raw ego (no normalization)
    k_gather<<<(NSLOT * 64 + 255) / 256, 256, 0, stream>>>(ego, users, pos, neg, out, 0, 0);

    for (int k = 0; k < 3; k++) {
        k_spmm<<<NTOT / 4, 256, 0, stream>>>(rp, ecv, ego, side);
        k_layer<<<NTOT / 4, 256, 0, stream>>>(side, ego,
            W_gc + (size_t)k * 4096, b_gc + (size_t)k * 64,
            W_bi + (size_t)k * 4096, b_bi + (size_t)k * 64);
        k_gather<<<(NSLOT * 64 + 255) / 256, 256, 0, stream>>>(ego, users, pos, neg, out, 64 * (k + 1), 1);
    }
}

// Round 3
// 1398.671 us; speedup vs baseline: 1.1278x; 1.0886x over previous
//
#include <hip/hip_runtime.h>
#include <hip/hip_bf16.h>

#define N_USERC 50000
#define N_ITEMC 50000
#define NTOT    100000
#define NNZC    3200000
#define EMBC    64
#define BATCHC  4096
#define NSLOT   (3*BATCHC)
#define XCDS    8
#define ROWS_PER_XCD (NTOT/XCDS)   // 12500

__device__ __forceinline__ float bf2f(unsigned short u) {
    return __int_as_float(((int)u) << 16);
}
__device__ __forceinline__ unsigned short f2bf(float f) {
    __hip_bfloat16 h = __float2bfloat16(f);      // RTNE
    return *(unsigned short*)&h;
}

// ---------------- init: ego = concat(user_emb, item_emb), + bf16 mirror ----------------
__global__ void k_init_ego(const float4* __restrict__ ue, const float4* __restrict__ ie,
                           float4* __restrict__ ego, ushort4* __restrict__ xb) {
    long i = (long)blockIdx.x * blockDim.x + threadIdx.x;          // float4 index
    const long nu4 = (long)N_USERC * EMBC / 4;
    const long tot4 = (long)NTOT * EMBC / 4;
    if (i < tot4) {
        float4 v = (i < nu4) ? ue[i] : ie[i - nu4];
        ego[i] = v;
        ushort4 b; b.x = f2bf(v.x); b.y = f2bf(v.y); b.z = f2bf(v.z); b.w = f2bf(v.w);
        xb[i] = b;
    }
}

// ---------------- CSR build ----------------
__global__ void k_zero_cnt(int* cnt) {
    int i = blockIdx.x * blockDim.x + threadIdx.x;
    if (i < NTOT) cnt[i] = 0;
}

__global__ void k_hist(const int* __restrict__ row, int* __restrict__ cnt) {
    int e = blockIdx.x * blockDim.x + threadIdx.x;
    if (e < NNZC) atomicAdd(&cnt[__builtin_nontemporal_load(row + e)], 1);
}

// per-block exclusive scan (256 elems/block); writes block totals
__global__ void k_scan1(const int* __restrict__ cnt, int* __restrict__ rp, int* __restrict__ bsum) {
    __shared__ int sm[256];
    int i = blockIdx.x * 256 + threadIdx.x;
    int v = (i < NTOT) ? cnt[i] : 0;
    sm[threadIdx.x] = v;
    __syncthreads();
    for (int off = 1; off < 256; off <<= 1) {
        int t = (threadIdx.x >= off) ? sm[threadIdx.x - off] : 0;
        __syncthreads();
        sm[threadIdx.x] += t;
        __syncthreads();
    }
    if (i < NTOT) rp[i] = sm[threadIdx.x] - v;   // exclusive within block
    if (threadIdx.x == 255) bsum[blockIdx.x] = sm[255];
}

__global__ void k_scan2(int* bsum, int nb) {
    __shared__ int sm[512];
    int v = (threadIdx.x < nb) ? bsum[threadIdx.x] : 0;
    sm[threadIdx.x] = v;
    __syncthreads();
    for (int off = 1; off < 512; off <<= 1) {
        int t = (threadIdx.x >= off) ? sm[threadIdx.x - off] : 0;
        __syncthreads();
        sm[threadIdx.x] += t;
        __syncthreads();
    }
    if (threadIdx.x < nb) bsum[threadIdx.x] = sm[threadIdx.x] - v;  // exclusive
}

__global__ void k_scan3(int* __restrict__ rp, const int* __restrict__ bsum, int* __restrict__ cursor) {
    int i = blockIdx.x * 256 + threadIdx.x;
    if (i < NTOT) {
        int v = rp[i] + bsum[blockIdx.x];
        rp[i] = v;
        cursor[i] = v;
    }
    if (i == 0) rp[NTOT] = NNZC;
}

// XCD-partitioned packed scatter: group g = blockIdx&7 handles rows [g*12500,(g+1)*12500)
// -> each XCD's stores land in a contiguous 1/8 of ecv (XCD-local dirty lines).
__global__ __launch_bounds__(256) void k_scatter(const int* __restrict__ row, const int* __restrict__ col,
                                                 const float* __restrict__ val, int* __restrict__ cursor,
                                                 long* __restrict__ ecv) {
    int g = blockIdx.x & 7;
    int chunk = blockIdx.x >> 3;
    int lo = g * ROWS_PER_XCD, hi = lo + ROWS_PER_XCD;
    int base = chunk * 1024;
    #pragma unroll
    for (int it = 0; it < 4; ++it) {
        int e = base + it * 256 + threadIdx.x;
        int r = __builtin_nontemporal_load(row + e);
        if (r >= lo && r < hi) {
            int c = __builtin_nontemporal_load(col + e);
            float v = __builtin_nontemporal_load(val + e);
            int p = atomicAdd(&cursor[r], 1);
            ecv[p] = ((long)__float_as_int(v) << 32) | (unsigned int)c;
        }
    }
}

// ---------------- SpMM: one wave per row, lane = emb dim, bf16 gather source ----------------
__global__ __launch_bounds__(256) void k_spmm(const int* __restrict__ rp, const long* __restrict__ ecv,
                                              const unsigned short* __restrict__ xb, float* __restrict__ side) {
    int r = (blockIdx.x * blockDim.x + threadIdx.x) >> 6;   // row
    int lane = threadIdx.x & 63;
    if (r >= NTOT) return;
    int s = rp[r], e = rp[r + 1];
    float acc = 0.f;
    int j = s;
    for (; j + 4 <= e; j += 4) {
        long p0 = __builtin_nontemporal_load(ecv + j);
        long p1 = __builtin_nontemporal_load(ecv + j + 1);
        long p2 = __builtin_nontemporal_load(ecv + j + 2);
        long p3 = __builtin_nontemporal_load(ecv + j + 3);
        float x0 = bf2f(xb[(long)(int)p0 * EMBC + lane]);
        float x1 = bf2f(xb[(long)(int)p1 * EMBC + lane]);
        float x2 = bf2f(xb[(long)(int)p2 * EMBC + lane]);
        float x3 = bf2f(xb[(long)(int)p3 * EMBC + lane]);
        acc += __int_as_float((int)(p0 >> 32)) * x0;
        acc += __int_as_float((int)(p1 >> 32)) * x1;
        acc += __int_as_float((int)(p2 >> 32)) * x2;
        acc += __int_as_float((int)(p3 >> 32)) * x3;
    }
    for (; j < e; ++j) {
        long p0 = __builtin_nontemporal_load(ecv + j);
        acc += __int_as_float((int)(p0 >> 32)) * bf2f(xb[(long)(int)p0 * EMBC + lane]);
    }
    side[(long)r * EMBC + lane] = acc;
}

// ------------- fused: sum_emb + bi_emb + leaky_relu, in-place ego update + bf16 mirror -------------
__global__ __launch_bounds__(256) void k_layer(const float* __restrict__ side, float* __restrict__ ego,
                                               unsigned short* __restrict__ xb,
                                               const float* __restrict__ Wgc, const float* __restrict__ bgc,
                                               const float* __restrict__ Wbi, const float* __restrict__ bbi) {
    __shared__ float sWgc[64 * 64];
    __shared__ float sWbi[64 * 64];
    __shared__ float sb[128];
    for (int i = threadIdx.x; i < 4096; i += 256) { sWgc[i] = Wgc[i]; sWbi[i] = Wbi[i]; }
    if (threadIdx.x < 128) sb[threadIdx.x] = (threadIdx.x < 64) ? bgc[threadIdx.x] : bbi[threadIdx.x - 64];
    __syncthreads();
    int r = (blockIdx.x * blockDim.x + threadIdx.x) >> 6;   // 4 rows per block, grid=25000 exact
    int lane = threadIdx.x & 63;
    float s = side[(long)r * 64 + lane];
    float e = ego[(long)r * 64 + lane];
    float m = e * s;
    float accg = sb[lane], accb = sb[64 + lane];
    #pragma unroll 8
    for (int d = 0; d < 64; d++) {
        float sv = __shfl(s, d);
        float mv = __shfl(m, d);
        accg += sv * sWgc[d * 64 + lane];
        accb += mv * sWbi[d * 64 + lane];
    }
    float xv = accg + accb;
    float o = (xv > 0.f) ? xv : 0.2f * xv;
    ego[(long)r * 64 + lane] = o;
    xb[(long)r * 64 + lane] = f2bf(o);
}

// ------------- gather batch rows (optionally L2-normalized) into d_out -------------
__global__ __launch_bounds__(256) void k_gather(const float* __restrict__ ego,
                                                const int* __restrict__ users,
                                                const int* __restrict__ pos,
                                                const int* __restrict__ neg,
                                                float* __restrict__ out, int colOff, int normalize) {
    int slot = (blockIdx.x * blockDim.x + threadIdx.x) >> 6;
    int lane = threadIdx.x & 63;
    if (slot >= NSLOT) return;
    int row;
    if (slot < BATCHC)          row = users[slot];
    else if (slot < 2 * BATCHC) row = N_USERC + pos[slot - BATCHC];
    else                        row = N_USERC + neg[slot - 2 * BATCHC];
    float v = ego[(long)row * 64 + lane];
    if (normalize) {
        float ss = v * v;
        for (int off = 32; off > 0; off >>= 1) ss += __shfl_xor(ss, off);
        float nrm = fmaxf(sqrtf(ss), 1e-12f);
        v = v / nrm;
    }
    out[(long)slot * 256 + colOff + lane] = v;
}

extern "C" void kernel_launch(void* const* d_in, const int* in_sizes, int n_in,
                              void* d_out, int out_size, void* d_ws, size_t ws_size,
                              hipStream_t stream) {
    const int*   users   = (const int*)d_in[0];
    const int*   pos     = (const int*)d_in[1];
    const int*   neg     = (const int*)d_in[2];
    const int*   adj_row = (const int*)d_in[3];
    const int*   adj_col = (const int*)d_in[4];
    const float* adj_val = (const float*)d_in[5];
    const float* user_emb = (const float*)d_in[6];
    const float* item_emb = (const float*)d_in[7];
    const float* W_gc = (const float*)d_in[8];
    const float* b_gc = (const float*)d_in[9];
    const float* W_bi = (const float*)d_in[10];
    const float* b_bi = (const float*)d_in[11];
    float* out = (float*)d_out;

    // workspace carve-up (~91 MB)
    char* p = (char*)d_ws;
    float* ego  = (float*)p;               p += (size_t)NTOT * EMBC * 4;
    float* side = (float*)p;               p += (size_t)NTOT * EMBC * 4;
    long*  ecv  = (long*)p;                p += (size_t)NNZC * 8;     // packed (col,val)
    unsigned short* xb = (unsigned short*)p; p += (size_t)NTOT * EMBC * 2;  // bf16 mirror of ego
    int*   cnt  = (int*)p;                 p += (size_t)NTOT * 4;
    int*   rp   = (int*)p;                 p += (size_t)(NTOT + 1) * 4 + 60;
    int*   cursor = (int*)p;               p += (size_t)NTOT * 4;
    int*   bsum = (int*)p;                 p += 2048;

    const int NB_SCAN = (NTOT + 255) / 256;   // 391

    // init ego (+bf16 mirror)
    k_init_ego<<<(NTOT * EMBC / 4 + 255) / 256, 256, 0, stream>>>(
        (const float4*)user_emb, (const float4*)item_emb, (float4*)ego, (ushort4*)xb);

    // CSR build
    k_zero_cnt<<<NB_SCAN, 256, 0, stream>>>(cnt);
    k_hist<<<NNZC / 256, 256, 0, stream>>>(adj_row, cnt);
    k_scan1<<<NB_SCAN, 256, 0, stream>>>(cnt, rp, bsum);
    k_scan2<<<1, 512, 0, stream>>>(bsum, NB_SCAN);
    k_scan3<<<NB_SCAN, 256, 0, stream>>>(rp, bsum, cursor);
    k_scatter<<<(NNZC / 1024) * XCDS, 256, 0, stream>>>(adj_row, adj_col, adj_val, cursor, ecv);

    // layer-0 slice of all_embs = raw ego (no normalization)
    k_gather<<<(NSLOT * 64 + 255) / 256, 256, 0, stream>>>(ego, users, pos, neg, out, 0, 0);

    for (int k = 0; k < 3; k++) {
        k_spmm<<<NTOT / 4, 256, 0, stream>>>(rp, ecv, xb, side);
        k_layer<<<NTOT / 4, 256, 0, stream>>>(side, ego, xb,
            W_gc + (size_t)k * 4096, b_gc + (size_t)k * 64,
            W_bi + (size_t)k * 4096, b_bi + (size_t)k * 64);
        k_gather<<<(NSLOT * 64 + 255) / 256, 256, 0, stream>>>(ego, users, pos, neg, out, 64 * (k + 1), 1);
    }
}

// Round 4
// 860.961 us; speedup vs baseline: 1.8322x; 1.6245x over previous
//
#include <hip/hip_runtime.h>
#include <hip/hip_bf16.h>

#define N_USERC 50000
#define N_ITEMC 50000
#define NTOT    100000
#define NNZC    3200000
#define EMBC    64
#define BATCHC  4096
#define NSLOT   (3*BATCHC)
#define XCDS    8
#define ROWS_PER_XCD (NTOT/XCDS)   // 12500

typedef __attribute__((ext_vector_type(4))) float floatx4;
typedef __attribute__((ext_vector_type(8))) short shortx8;   // 8 bf16 = 4 VGPRs

__device__ __forceinline__ float bf2f(unsigned short u) {
    return __int_as_float(((int)u) << 16);
}
__device__ __forceinline__ unsigned short f2bf(float f) {
    __hip_bfloat16 h = __float2bfloat16(f);      // RTNE
    return *(unsigned short*)&h;
}

// ---------------- init: ego = concat(user_emb, item_emb), + bf16 mirror ----------------
__global__ void k_init_ego(const float4* __restrict__ ue, const float4* __restrict__ ie,
                           float4* __restrict__ ego, ushort4* __restrict__ xb) {
    long i = (long)blockIdx.x * blockDim.x + threadIdx.x;          // float4 index
    const long nu4 = (long)N_USERC * EMBC / 4;
    const long tot4 = (long)NTOT * EMBC / 4;
    if (i < tot4) {
        float4 v = (i < nu4) ? ue[i] : ie[i - nu4];
        ego[i] = v;
        ushort4 b; b.x = f2bf(v.x); b.y = f2bf(v.y); b.z = f2bf(v.z); b.w = f2bf(v.w);
        xb[i] = b;
    }
}

// ---------------- CSR build ----------------
__global__ void k_zero_cnt(int* cnt) {
    int i = blockIdx.x * blockDim.x + threadIdx.x;
    if (i < NTOT) cnt[i] = 0;
}

__global__ void k_hist(const int* __restrict__ row, int* __restrict__ cnt) {
    int e = blockIdx.x * blockDim.x + threadIdx.x;
    if (e < NNZC) atomicAdd(&cnt[__builtin_nontemporal_load(row + e)], 1);
}

__global__ void k_scan1(const int* __restrict__ cnt, int* __restrict__ rp, int* __restrict__ bsum) {
    __shared__ int sm[256];
    int i = blockIdx.x * 256 + threadIdx.x;
    int v = (i < NTOT) ? cnt[i] : 0;
    sm[threadIdx.x] = v;
    __syncthreads();
    for (int off = 1; off < 256; off <<= 1) {
        int t = (threadIdx.x >= off) ? sm[threadIdx.x - off] : 0;
        __syncthreads();
        sm[threadIdx.x] += t;
        __syncthreads();
    }
    if (i < NTOT) rp[i] = sm[threadIdx.x] - v;
    if (threadIdx.x == 255) bsum[blockIdx.x] = sm[255];
}

__global__ void k_scan2(int* bsum, int nb) {
    __shared__ int sm[512];
    int v = (threadIdx.x < nb) ? bsum[threadIdx.x] : 0;
    sm[threadIdx.x] = v;
    __syncthreads();
    for (int off = 1; off < 512; off <<= 1) {
        int t = (threadIdx.x >= off) ? sm[threadIdx.x - off] : 0;
        __syncthreads();
        sm[threadIdx.x] += t;
        __syncthreads();
    }
    if (threadIdx.x < nb) bsum[threadIdx.x] = sm[threadIdx.x] - v;
}

__global__ void k_scan3(int* __restrict__ rp, const int* __restrict__ bsum, int* __restrict__ cursor) {
    int i = blockIdx.x * 256 + threadIdx.x;
    if (i < NTOT) {
        int v = rp[i] + bsum[blockIdx.x];
        rp[i] = v;
        cursor[i] = v;
    }
    if (i == 0) rp[NTOT] = NNZC;
}

// XCD-partitioned packed scatter
__global__ __launch_bounds__(256) void k_scatter(const int* __restrict__ row, const int* __restrict__ col,
                                                 const float* __restrict__ val, int* __restrict__ cursor,
                                                 long* __restrict__ ecv) {
    int g = blockIdx.x & 7;
    int chunk = blockIdx.x >> 3;
    int lo = g * ROWS_PER_XCD, hi = lo + ROWS_PER_XCD;
    int base = chunk * 1024;
    #pragma unroll
    for (int it = 0; it < 4; ++it) {
        int e = base + it * 256 + threadIdx.x;
        int r = __builtin_nontemporal_load(row + e);
        if (r >= lo && r < hi) {
            int c = __builtin_nontemporal_load(col + e);
            float v = __builtin_nontemporal_load(val + e);
            int p = atomicAdd(&cursor[r], 1);
            ecv[p] = ((long)__float_as_int(v) << 32) | (unsigned int)c;
        }
    }
}

// ---------------- SpMM: one wave per row, bf16 gather source, bf16 side output ----------------
__global__ __launch_bounds__(256) void k_spmm(const int* __restrict__ rp, const long* __restrict__ ecv,
                                              const unsigned short* __restrict__ xb,
                                              unsigned short* __restrict__ side_bf) {
    int r = (blockIdx.x * blockDim.x + threadIdx.x) >> 6;
    int lane = threadIdx.x & 63;
    if (r >= NTOT) return;
    int s = rp[r], e = rp[r + 1];
    float acc = 0.f;
    int j = s;
    for (; j + 4 <= e; j += 4) {
        long p0 = __builtin_nontemporal_load(ecv + j);
        long p1 = __builtin_nontemporal_load(ecv + j + 1);
        long p2 = __builtin_nontemporal_load(ecv + j + 2);
        long p3 = __builtin_nontemporal_load(ecv + j + 3);
        float x0 = bf2f(xb[(long)(int)p0 * EMBC + lane]);
        float x1 = bf2f(xb[(long)(int)p1 * EMBC + lane]);
        float x2 = bf2f(xb[(long)(int)p2 * EMBC + lane]);
        float x3 = bf2f(xb[(long)(int)p3 * EMBC + lane]);
        acc += __int_as_float((int)(p0 >> 32)) * x0;
        acc += __int_as_float((int)(p1 >> 32)) * x1;
        acc += __int_as_float((int)(p2 >> 32)) * x2;
        acc += __int_as_float((int)(p3 >> 32)) * x3;
    }
    for (; j < e; ++j) {
        long p0 = __builtin_nontemporal_load(ecv + j);
        acc += __int_as_float((int)(p0 >> 32)) * bf2f(xb[(long)(int)p0 * EMBC + lane]);
    }
    side_bf[(long)r * EMBC + lane] = f2bf(acc);
}

// ------------- MFMA layer: [sum_emb + bi_emb + bias] -> leaky_relu, updates ego + xb -------------
#define RPB 128   // rows per block
#define LDP 72    // LDS row stride in shorts (144 B = 9*16 B: 16B-aligned, breaks bank stride)
__global__ __launch_bounds__(256) void k_layer_mfma(
    const unsigned short* __restrict__ side_bf, float* __restrict__ ego,
    unsigned short* __restrict__ xb,
    const float* __restrict__ Wgc, const float* __restrict__ bgc,
    const float* __restrict__ Wbi, const float* __restrict__ bbi)
{
    __shared__ unsigned short sS[RPB * LDP];    // s  (side) bf16
    __shared__ unsigned short sM[RPB * LDP];    // m = ego*side bf16
    __shared__ unsigned short sWg[64 * LDP];    // Wgc^T [c][d] bf16
    __shared__ unsigned short sWb[64 * LDP];    // Wbi^T [c][d] bf16
    __shared__ float sBias[64];

    int tid = threadIdx.x;
    int row0 = blockIdx.x * RPB;

    // stage W transposed (one-time per block, W is L2-resident)
    for (int i = tid; i < 4096; i += 256) {
        int d = i >> 6, c = i & 63;
        sWg[c * LDP + d] = f2bf(Wgc[i]);
        sWb[c * LDP + d] = f2bf(Wbi[i]);
    }
    if (tid < 64) sBias[tid] = bgc[tid] + bbi[tid];

    // stage s and m: items = RPB rows x 8 chunks of 8 elems
    #pragma unroll
    for (int it = 0; it < (RPB * 8) / 256; ++it) {
        int item = it * 256 + tid;
        int r = item >> 3, ch = item & 7;
        long grow = row0 + r;
        uint4 sv = make_uint4(0, 0, 0, 0);
        float4 e0 = make_float4(0, 0, 0, 0), e1 = make_float4(0, 0, 0, 0);
        if (grow < NTOT) {
            sv = *(const uint4*)(side_bf + grow * 64 + ch * 8);
            e0 = *(const float4*)(ego + grow * 64 + ch * 8);
            e1 = *(const float4*)(ego + grow * 64 + ch * 8 + 4);
        }
        unsigned short ss[8] = {(unsigned short)(sv.x & 0xffff), (unsigned short)(sv.x >> 16),
                                (unsigned short)(sv.y & 0xffff), (unsigned short)(sv.y >> 16),
                                (unsigned short)(sv.z & 0xffff), (unsigned short)(sv.z >> 16),
                                (unsigned short)(sv.w & 0xffff), (unsigned short)(sv.w >> 16)};
        float eg[8] = {e0.x, e0.y, e0.z, e0.w, e1.x, e1.y, e1.z, e1.w};
        uint4 mv;
        unsigned int m01 = f2bf(eg[0] * bf2f(ss[0])) | ((unsigned int)f2bf(eg[1] * bf2f(ss[1])) << 16);
        unsigned int m23 = f2bf(eg[2] * bf2f(ss[2])) | ((unsigned int)f2bf(eg[3] * bf2f(ss[3])) << 16);
        unsigned int m45 = f2bf(eg[4] * bf2f(ss[4])) | ((unsigned int)f2bf(eg[5] * bf2f(ss[5])) << 16);
        unsigned int m67 = f2bf(eg[6] * bf2f(ss[6])) | ((unsigned int)f2bf(eg[7] * bf2f(ss[7])) << 16);
        mv.x = m01; mv.y = m23; mv.z = m45; mv.w = m67;
        *(uint4*)(sS + r * LDP + ch * 8) = sv;
        *(uint4*)(sM + r * LDP + ch * 8) = mv;
    }
    __syncthreads();

    int wave = tid >> 6, lane = tid & 63;
    int quad = lane >> 4, l16 = lane & 15;

    floatx4 accG[2][4], accB[2][4];
    #pragma unroll
    for (int rt = 0; rt < 2; rt++)
        #pragma unroll
        for (int ct = 0; ct < 4; ct++) {
            accG[rt][ct] = (floatx4){0.f, 0.f, 0.f, 0.f};
            accB[rt][ct] = (floatx4){0.f, 0.f, 0.f, 0.f};
        }

    #pragma unroll
    for (int kc = 0; kc < 64; kc += 32) {
        shortx8 aS[2], aM[2];
        #pragma unroll
        for (int rt = 0; rt < 2; rt++) {
            int r = wave * 32 + rt * 16 + l16;
            aS[rt] = *(const shortx8*)(sS + r * LDP + kc + quad * 8);
            aM[rt] = *(const shortx8*)(sM + r * LDP + kc + quad * 8);
        }
        #pragma unroll
        for (int ct = 0; ct < 4; ct++) {
            int c = ct * 16 + l16;
            shortx8 bG = *(const shortx8*)(sWg + c * LDP + kc + quad * 8);
            shortx8 bB = *(const shortx8*)(sWb + c * LDP + kc + quad * 8);
            #pragma unroll
            for (int rt = 0; rt < 2; rt++) {
                accG[rt][ct] = __builtin_amdgcn_mfma_f32_16x16x32_bf16(aS[rt], bG, accG[rt][ct], 0, 0, 0);
                accB[rt][ct] = __builtin_amdgcn_mfma_f32_16x16x32_bf16(aM[rt], bB, accB[rt][ct], 0, 0, 0);
            }
        }
    }

    // epilogue: bias + leaky relu; C/D layout col=lane&15, row=quad*4+reg
    #pragma unroll
    for (int rt = 0; rt < 2; rt++)
        #pragma unroll
        for (int ct = 0; ct < 4; ct++) {
            int c = ct * 16 + l16;
            float bs = sBias[c];
            #pragma unroll
            for (int reg = 0; reg < 4; reg++) {
                int r = wave * 32 + rt * 16 + quad * 4 + reg;
                long grow = row0 + r;
                if (grow < NTOT) {
                    float v = accG[rt][ct][reg] + accB[rt][ct][reg] + bs;
                    float o = (v > 0.f) ? v : 0.2f * v;
                    ego[grow * 64 + c] = o;
                    xb[grow * 64 + c] = f2bf(o);
                }
            }
        }
}

// ------------- gather batch rows (optionally L2-normalized) into d_out -------------
__global__ __launch_bounds__(256) void k_gather(const float* __restrict__ ego,
                                                const int* __restrict__ users,
                                                const int* __restrict__ pos,
                                                const int* __restrict__ neg,
                                                float* __restrict__ out, int colOff, int normalize) {
    int slot = (blockIdx.x * blockDim.x + threadIdx.x) >> 6;
    int lane = threadIdx.x & 63;
    if (slot >= NSLOT) return;
    int row;
    if (slot < BATCHC)          row = users[slot];
    else if (slot < 2 * BATCHC) row = N_USERC + pos[slot - BATCHC];
    else                        row = N_USERC + neg[slot - 2 * BATCHC];
    float v = ego[(long)row * 64 + lane];
    if (normalize) {
        float ss = v * v;
        for (int off = 32; off > 0; off >>= 1) ss += __shfl_xor(ss, off);
        float nrm = fmaxf(sqrtf(ss), 1e-12f);
        v = v / nrm;
    }
    out[(long)slot * 256 + colOff + lane] = v;
}

extern "C" void kernel_launch(void* const* d_in, const int* in_sizes, int n_in,
                              void* d_out, int out_size, void* d_ws, size_t ws_size,
                              hipStream_t stream) {
    const int*   users   = (const int*)d_in[0];
    const int*   pos     = (const int*)d_in[1];
    const int*   neg     = (const int*)d_in[2];
    const int*   adj_row = (const int*)d_in[3];
    const int*   adj_col = (const int*)d_in[4];
    const float* adj_val = (const float*)d_in[5];
    const float* user_emb = (const float*)d_in[6];
    const float* item_emb = (const float*)d_in[7];
    const float* W_gc = (const float*)d_in[8];
    const float* b_gc = (const float*)d_in[9];
    const float* W_bi = (const float*)d_in[10];
    const float* b_bi = (const float*)d_in[11];
    float* out = (float*)d_out;

    // workspace carve-up (~78 MB)
    char* p = (char*)d_ws;
    float* ego  = (float*)p;                   p += (size_t)NTOT * EMBC * 4;
    unsigned short* side_bf = (unsigned short*)p; p += (size_t)NTOT * EMBC * 2;
    long*  ecv  = (long*)p;                    p += (size_t)NNZC * 8;
    unsigned short* xb = (unsigned short*)p;   p += (size_t)NTOT * EMBC * 2;
    int*   cnt  = (int*)p;                     p += (size_t)NTOT * 4;
    int*   rp   = (int*)p;                     p += (size_t)(NTOT + 1) * 4 + 60;
    int*   cursor = (int*)p;                   p += (size_t)NTOT * 4;
    int*   bsum = (int*)p;                     p += 2048;

    const int NB_SCAN = (NTOT + 255) / 256;   // 391

    k_init_ego<<<(NTOT * EMBC / 4 + 255) / 256, 256, 0, stream>>>(
        (const float4*)user_emb, (const float4*)item_emb, (float4*)ego, (ushort4*)xb);

    k_zero_cnt<<<NB_SCAN, 256, 0, stream>>>(cnt);
    k_hist<<<NNZC / 256, 256, 0, stream>>>(adj_row, cnt);
    k_scan1<<<NB_SCAN, 256, 0, stream>>>(cnt, rp, bsum);
    k_scan2<<<1, 512, 0, stream>>>(bsum, NB_SCAN);
    k_scan3<<<NB_SCAN, 256, 0, stream>>>(rp, bsum, cursor);
    k_scatter<<<(NNZC / 1024) * XCDS, 256, 0, stream>>>(adj_row, adj_col, adj_val, cursor, ecv);

    // layer-0 slice of all_embs = raw ego (no normalization)
    k_gather<<<(NSLOT * 64 + 255) / 256, 256, 0, stream>>>(ego, users, pos, neg, out, 0, 0);

    const int NB_LAYER = (NTOT + RPB - 1) / RPB;   // 782
    for (int k = 0; k < 3; k++) {
        k_spmm<<<NTOT / 4, 256, 0, stream>>>(rp, ecv, xb, side_bf);
        k_layer_mfma<<<NB_LAYER, 256, 0, stream>>>(side_bf, ego, xb,
            W_gc + (size_t)k * 4096, b_gc + (size_t)k * 64,
            W_bi + (size_t)k * 4096, b_bi + (size_t)k * 64);
        k_gather<<<(NSLOT * 64 + 255) / 256, 256, 0, stream>>>(ego, users, pos, neg, out, 64 * (k + 1), 1);
    }
}

// Round 5
// 680.415 us; speedup vs baseline: 2.3184x; 1.2653x over previous
//
#include <hip/hip_runtime.h>
#include <hip/hip_bf16.h>

#define N_USERC 50000
#define N_ITEMC 50000
#define NTOT    100000
#define NNZC    3200000
#define EMBC    64
#define BATCHC  4096
#define NSLOT   (3*BATCHC)
#define XCDS    8
#define ROWS_PER_XCD (NTOT/XCDS)   // 12500

typedef __attribute__((ext_vector_type(4))) float floatx4;
typedef __attribute__((ext_vector_type(8))) short shortx8;   // 8 bf16 = 4 VGPRs

__device__ __forceinline__ float bf2f(unsigned short u) {
    return __int_as_float(((int)u) << 16);
}
__device__ __forceinline__ unsigned short f2bf(float f) {
    __hip_bfloat16 h = __float2bfloat16(f);      // RTNE
    return *(unsigned short*)&h;
}

// ---------------- init: xb = bf16(concat(user_emb, item_emb)) ----------------
__global__ void k_init_xb(const float4* __restrict__ ue, const float4* __restrict__ ie,
                          ushort4* __restrict__ xb) {
    long i = (long)blockIdx.x * blockDim.x + threadIdx.x;          // float4 index
    const long nu4 = (long)N_USERC * EMBC / 4;
    const long tot4 = (long)NTOT * EMBC / 4;
    if (i < tot4) {
        float4 v = (i < nu4) ? ue[i] : ie[i - nu4];
        ushort4 b; b.x = f2bf(v.x); b.y = f2bf(v.y); b.z = f2bf(v.z); b.w = f2bf(v.w);
        xb[i] = b;
    }
}

// ---------------- CSR build ----------------
__global__ void k_zero_cnt(int* cnt) {
    int i = blockIdx.x * blockDim.x + threadIdx.x;
    if (i < NTOT) cnt[i] = 0;
}

__global__ void k_hist(const int* __restrict__ row, int* __restrict__ cnt) {
    int e = blockIdx.x * blockDim.x + threadIdx.x;
    if (e < NNZC) atomicAdd(&cnt[__builtin_nontemporal_load(row + e)], 1);
}

__global__ void k_scan1(const int* __restrict__ cnt, int* __restrict__ rp, int* __restrict__ bsum) {
    __shared__ int sm[256];
    int i = blockIdx.x * 256 + threadIdx.x;
    int v = (i < NTOT) ? cnt[i] : 0;
    sm[threadIdx.x] = v;
    __syncthreads();
    for (int off = 1; off < 256; off <<= 1) {
        int t = (threadIdx.x >= off) ? sm[threadIdx.x - off] : 0;
        __syncthreads();
        sm[threadIdx.x] += t;
        __syncthreads();
    }
    if (i < NTOT) rp[i] = sm[threadIdx.x] - v;
    if (threadIdx.x == 255) bsum[blockIdx.x] = sm[255];
}

__global__ void k_scan2(int* bsum, int nb) {
    __shared__ int sm[512];
    int v = (threadIdx.x < nb) ? bsum[threadIdx.x] : 0;
    sm[threadIdx.x] = v;
    __syncthreads();
    for (int off = 1; off < 512; off <<= 1) {
        int t = (threadIdx.x >= off) ? sm[threadIdx.x - off] : 0;
        __syncthreads();
        sm[threadIdx.x] += t;
        __syncthreads();
    }
    if (threadIdx.x < nb) bsum[threadIdx.x] = sm[threadIdx.x] - v;
}

__global__ void k_scan3(int* __restrict__ rp, const int* __restrict__ bsum, int* __restrict__ cursor) {
    int i = blockIdx.x * 256 + threadIdx.x;
    if (i < NTOT) {
        int v = rp[i] + bsum[blockIdx.x];
        rp[i] = v;
        cursor[i] = v;
    }
    if (i == 0) rp[NTOT] = NNZC;
}

// XCD-partitioned packed scatter
__global__ __launch_bounds__(256) void k_scatter(const int* __restrict__ row, const int* __restrict__ col,
                                                 const float* __restrict__ val, int* __restrict__ cursor,
                                                 long* __restrict__ ecv) {
    int g = blockIdx.x & 7;
    int chunk = blockIdx.x >> 3;
    int lo = g * ROWS_PER_XCD, hi = lo + ROWS_PER_XCD;
    int base = chunk * 1024;
    #pragma unroll
    for (int it = 0; it < 4; ++it) {
        int e = base + it * 256 + threadIdx.x;
        int r = __builtin_nontemporal_load(row + e);
        if (r >= lo && r < hi) {
            int c = __builtin_nontemporal_load(col + e);
            float v = __builtin_nontemporal_load(val + e);
            int p = atomicAdd(&cursor[r], 1);
            ecv[p] = ((long)__float_as_int(v) << 32) | (unsigned int)c;
        }
    }
}

// ---------------- SpMM: one wave per row, 4 edges/step (16 lanes per edge) ----------------
// lane = q*16+t: quad q handles edge j+u*4+q, lane loads dims [4t..4t+3] (ushort4, 8B).
// 16 edges (2KB) in flight per wave per iteration; cross-quad shfl_xor reduction.
__global__ __launch_bounds__(256) void k_spmm(const int* __restrict__ rp, const long* __restrict__ ecv,
                                              const unsigned short* __restrict__ xb,
                                              unsigned short* __restrict__ side_bf) {
    int r = (blockIdx.x * blockDim.x + threadIdx.x) >> 6;
    int lane = threadIdx.x & 63;
    if (r >= NTOT) return;
    int q = lane >> 4;
    int t4 = (lane & 15) * 4;
    int s = rp[r], e = rp[r + 1];
    float a0 = 0.f, a1 = 0.f, a2 = 0.f, a3 = 0.f;
    for (int j = s; j < e; j += 16) {
        long pk[4];
        bool vm[4];
        #pragma unroll
        for (int u = 0; u < 4; ++u) {
            int je = j + u * 4 + q;
            vm[u] = (je < e);
            pk[u] = __builtin_nontemporal_load(ecv + (vm[u] ? je : 0));
        }
        ushort4 xv[4];
        #pragma unroll
        for (int u = 0; u < 4; ++u)
            xv[u] = *(const ushort4*)(xb + (long)(int)pk[u] * EMBC + t4);
        #pragma unroll
        for (int u = 0; u < 4; ++u) {
            float w = vm[u] ? __int_as_float((int)(pk[u] >> 32)) : 0.f;
            a0 += w * bf2f(xv[u].x);
            a1 += w * bf2f(xv[u].y);
            a2 += w * bf2f(xv[u].z);
            a3 += w * bf2f(xv[u].w);
        }
    }
    // combine the 4 quads
    a0 += __shfl_xor(a0, 16); a1 += __shfl_xor(a1, 16); a2 += __shfl_xor(a2, 16); a3 += __shfl_xor(a3, 16);
    a0 += __shfl_xor(a0, 32); a1 += __shfl_xor(a1, 32); a2 += __shfl_xor(a2, 32); a3 += __shfl_xor(a3, 32);
    if (lane < 16) {
        ushort4 o; o.x = f2bf(a0); o.y = f2bf(a1); o.z = f2bf(a2); o.w = f2bf(a3);
        *(ushort4*)(side_bf + (long)r * EMBC + t4) = o;
    }
}

// ------------- MFMA layer: [sum_emb + bi_emb + bias] -> leaky_relu, updates xb (bf16 state) -------------
#define RPB 128   // rows per block
#define LDP 72    // LDS row stride in shorts (144 B: 16B-aligned, breaks bank stride)
__global__ __launch_bounds__(256) void k_layer_mfma(
    const unsigned short* __restrict__ side_bf, unsigned short* __restrict__ xb,
    const float* __restrict__ Wgc, const float* __restrict__ bgc,
    const float* __restrict__ Wbi, const float* __restrict__ bbi)
{
    __shared__ unsigned short sS[RPB * LDP];    // s  (side) bf16
    __shared__ unsigned short sM[RPB * LDP];    // m = ego*side bf16
    __shared__ unsigned short sWg[64 * LDP];    // Wgc^T [c][d] bf16
    __shared__ unsigned short sWb[64 * LDP];    // Wbi^T [c][d] bf16
    __shared__ float sBias[64];

    int tid = threadIdx.x;
    int row0 = blockIdx.x * RPB;

    for (int i = tid; i < 4096; i += 256) {
        int d = i >> 6, c = i & 63;
        sWg[c * LDP + d] = f2bf(Wgc[i]);
        sWb[c * LDP + d] = f2bf(Wbi[i]);
    }
    if (tid < 64) sBias[tid] = bgc[tid] + bbi[tid];

    // stage s and m: RPB rows x 8 chunks of 8 elems
    #pragma unroll
    for (int it = 0; it < (RPB * 8) / 256; ++it) {
        int item = it * 256 + tid;
        int r = item >> 3, ch = item & 7;
        long grow = row0 + r;
        uint4 sv = make_uint4(0, 0, 0, 0), ev = make_uint4(0, 0, 0, 0);
        if (grow < NTOT) {
            sv = *(const uint4*)(side_bf + grow * 64 + ch * 8);
            ev = *(const uint4*)(xb + grow * 64 + ch * 8);
        }
        uint4 mv;
        mv.x = f2bf(bf2f(ev.x & 0xffff) * bf2f(sv.x & 0xffff)) |
               ((unsigned int)f2bf(bf2f(ev.x >> 16) * bf2f(sv.x >> 16)) << 16);
        mv.y = f2bf(bf2f(ev.y & 0xffff) * bf2f(sv.y & 0xffff)) |
               ((unsigned int)f2bf(bf2f(ev.y >> 16) * bf2f(sv.y >> 16)) << 16);
        mv.z = f2bf(bf2f(ev.z & 0xffff) * bf2f(sv.z & 0xffff)) |
               ((unsigned int)f2bf(bf2f(ev.z >> 16) * bf2f(sv.z >> 16)) << 16);
        mv.w = f2bf(bf2f(ev.w & 0xffff) * bf2f(sv.w & 0xffff)) |
               ((unsigned int)f2bf(bf2f(ev.w >> 16) * bf2f(sv.w >> 16)) << 16);
        *(uint4*)(sS + r * LDP + ch * 8) = sv;
        *(uint4*)(sM + r * LDP + ch * 8) = mv;
    }
    __syncthreads();

    int wave = tid >> 6, lane = tid & 63;
    int quad = lane >> 4, l16 = lane & 15;

    floatx4 accG[2][4], accB[2][4];
    #pragma unroll
    for (int rt = 0; rt < 2; rt++)
        #pragma unroll
        for (int ct = 0; ct < 4; ct++) {
            accG[rt][ct] = (floatx4){0.f, 0.f, 0.f, 0.f};
            accB[rt][ct] = (floatx4){0.f, 0.f, 0.f, 0.f};
        }

    #pragma unroll
    for (int kc = 0; kc < 64; kc += 32) {
        shortx8 aS[2], aM[2];
        #pragma unroll
        for (int rt = 0; rt < 2; rt++) {
            int r = wave * 32 + rt * 16 + l16;
            aS[rt] = *(const shortx8*)(sS + r * LDP + kc + quad * 8);
            aM[rt] = *(const shortx8*)(sM + r * LDP + kc + quad * 8);
        }
        #pragma unroll
        for (int ct = 0; ct < 4; ct++) {
            int c = ct * 16 + l16;
            shortx8 bG = *(const shortx8*)(sWg + c * LDP + kc + quad * 8);
            shortx8 bB = *(const shortx8*)(sWb + c * LDP + kc + quad * 8);
            #pragma unroll
            for (int rt = 0; rt < 2; rt++) {
                accG[rt][ct] = __builtin_amdgcn_mfma_f32_16x16x32_bf16(aS[rt], bG, accG[rt][ct], 0, 0, 0);
                accB[rt][ct] = __builtin_amdgcn_mfma_f32_16x16x32_bf16(aM[rt], bB, accB[rt][ct], 0, 0, 0);
            }
        }
    }

    // epilogue: bias + leaky relu; C/D layout col=lane&15, row=quad*4+reg
    #pragma unroll
    for (int rt = 0; rt < 2; rt++)
        #pragma unroll
        for (int ct = 0; ct < 4; ct++) {
            int c = ct * 16 + l16;
            float bs = sBias[c];
            #pragma unroll
            for (int reg = 0; reg < 4; reg++) {
                int r = wave * 32 + rt * 16 + quad * 4 + reg;
                long grow = row0 + r;
                if (grow < NTOT) {
                    float v = accG[rt][ct][reg] + accB[rt][ct][reg] + bs;
                    float o = (v > 0.f) ? v : 0.2f * v;
                    xb[grow * 64 + c] = f2bf(o);
                }
            }
        }
}

// ------------- gather batch rows (optionally L2-normalized) into d_out -------------
__global__ __launch_bounds__(256) void k_gather(const unsigned short* __restrict__ xb,
                                                const int* __restrict__ users,
                                                const int* __restrict__ pos,
                                                const int* __restrict__ neg,
                                                float* __restrict__ out, int colOff, int normalize) {
    int slot = (blockIdx.x * blockDim.x + threadIdx.x) >> 6;
    int lane = threadIdx.x & 63;
    if (slot >= NSLOT) return;
    int row;
    if (slot < BATCHC)          row = users[slot];
    else if (slot < 2 * BATCHC) row = N_USERC + pos[slot - BATCHC];
    else                        row = N_USERC + neg[slot - 2 * BATCHC];
    float v = bf2f(xb[(long)row * 64 + lane]);
    if (normalize) {
        float ss = v * v;
        for (int off = 32; off > 0; off >>= 1) ss += __shfl_xor(ss, off);
        float nrm = fmaxf(sqrtf(ss), 1e-12f);
        v = v / nrm;
    }
    out[(long)slot * 256 + colOff + lane] = v;
}

extern "C" void kernel_launch(void* const* d_in, const int* in_sizes, int n_in,
                              void* d_out, int out_size, void* d_ws, size_t ws_size,
                              hipStream_t stream) {
    const int*   users   = (const int*)d_in[0];
    const int*   pos     = (const int*)d_in[1];
    const int*   neg     = (const int*)d_in[2];
    const int*   adj_row = (const int*)d_in[3];
    const int*   adj_col = (const int*)d_in[4];
    const float* adj_val = (const float*)d_in[5];
    const float* user_emb = (const float*)d_in[6];
    const float* item_emb = (const float*)d_in[7];
    const float* W_gc = (const float*)d_in[8];
    const float* b_gc = (const float*)d_in[9];
    const float* W_bi = (const float*)d_in[10];
    const float* b_bi = (const float*)d_in[11];
    float* out = (float*)d_out;

    // workspace carve-up (~53 MB)
    char* p = (char*)d_ws;
    unsigned short* side_bf = (unsigned short*)p; p += (size_t)NTOT * EMBC * 2;
    long*  ecv  = (long*)p;                    p += (size_t)NNZC * 8;
    unsigned short* xb = (unsigned short*)p;   p += (size_t)NTOT * EMBC * 2;
    int*   cnt  = (int*)p;                     p += (size_t)NTOT * 4;
    int*   rp   = (int*)p;                     p += (size_t)(NTOT + 1) * 4 + 60;
    int*   cursor = (int*)p;                   p += (size_t)NTOT * 4;
    int*   bsum = (int*)p;                     p += 2048;

    const int NB_SCAN = (NTOT + 255) / 256;   // 391

    k_init_xb<<<(NTOT * EMBC / 4 + 255) / 256, 256, 0, stream>>>(
        (const float4*)user_emb, (const float4*)item_emb, (ushort4*)xb);

    k_zero_cnt<<<NB_SCAN, 256, 0, stream>>>(cnt);
    k_hist<<<NNZC / 256, 256, 0, stream>>>(adj_row, cnt);
    k_scan1<<<NB_SCAN, 256, 0, stream>>>(cnt, rp, bsum);
    k_scan2<<<1, 512, 0, stream>>>(bsum, NB_SCAN);
    k_scan3<<<NB_SCAN, 256, 0, stream>>>(rp, bsum, cursor);
    k_scatter<<<(NNZC / 1024) * XCDS, 256, 0, stream>>>(adj_row, adj_col, adj_val, cursor, ecv);

    // layer-0 slice of all_embs = raw ego (no normalization)
    k_gather<<<(NSLOT * 64 + 255) / 256, 256, 0, stream>>>(xb, users, pos, neg, out, 0, 0);

    const int NB_LAYER = (NTOT + RPB - 1) / RPB;   // 782
    for (int k = 0; k < 3; k++) {
        k_spmm<<<NTOT / 4, 256, 0, stream>>>(rp, ecv, xb, side_bf);
        k_layer_mfma<<<NB_LAYER, 256, 0, stream>>>(side_bf, xb,
            W_gc + (size_t)k * 4096, b_gc + (size_t)k * 64,
            W_bi + (size_t)k * 4096, b_bi + (size_t)k * 64);
        k_gather<<<(NSLOT * 64 + 255) / 256, 256, 0, stream>>>(xb, users, pos, neg, out, 64 * (k + 1), 1);
    }
}

// Round 7
// 601.067 us; speedup vs baseline: 2.6244x; 1.1320x over previous
//
#include <hip/hip_runtime.h>
#include <hip/hip_bf16.h>

#define N_USERC 50000
#define N_ITEMC 50000
#define NTOT    100000
#define NNZC    3200000
#define EMBC    64
#define BATCHC  4096
#define NSLOT   (3*BATCHC)
#define NBKT    196            // buckets of 512 rows
typedef unsigned long long u64;

typedef __attribute__((ext_vector_type(4))) float floatx4;
typedef __attribute__((ext_vector_type(4))) int   intx4;
typedef __attribute__((ext_vector_type(8))) short shortx8;   // 8 bf16 = 4 VGPRs

__device__ __forceinline__ float bf2f(unsigned short u) {
    return __int_as_float(((int)u) << 16);
}
__device__ __forceinline__ unsigned short f2bf(float f) {
    __hip_bfloat16 h = __float2bfloat16(f);      // RTNE
    return *(unsigned short*)&h;
}

// ---------------- init: xb = bf16(concat(user_emb, item_emb)) ----------------
__global__ void k_init_xb(const float4* __restrict__ ue, const float4* __restrict__ ie,
                          ushort4* __restrict__ xb) {
    long i = (long)blockIdx.x * blockDim.x + threadIdx.x;
    const long nu4 = (long)N_USERC * EMBC / 4;
    const long tot4 = (long)NTOT * EMBC / 4;
    if (i < tot4) {
        float4 v = (i < nu4) ? ue[i] : ie[i - nu4];
        ushort4 b; b.x = f2bf(v.x); b.y = f2bf(v.y); b.z = f2bf(v.z); b.w = f2bf(v.w);
        xb[i] = b;
    }
}

__global__ void k_zero_cnt(int* cnt) {
    int i = blockIdx.x * blockDim.x + threadIdx.x;
    if (i < NTOT) cnt[i] = 0;
}

// ---------------- pack edges to 8B (row|col|bf16val) + row histogram ----------------
__global__ __launch_bounds__(256) void k_pack_hist(const intx4* __restrict__ row4, const intx4* __restrict__ col4,
                                                   const floatx4* __restrict__ val4, int* __restrict__ cnt,
                                                   u64* __restrict__ pe) {
    int i = blockIdx.x * blockDim.x + threadIdx.x;   // group of 4 edges
    if (i >= NNZC / 4) return;
    intx4 r = __builtin_nontemporal_load(row4 + i);
    intx4 c = __builtin_nontemporal_load(col4 + i);
    floatx4 v = __builtin_nontemporal_load(val4 + i);
    atomicAdd(&cnt[r.x], 1);
    atomicAdd(&cnt[r.y], 1);
    atomicAdd(&cnt[r.z], 1);
    atomicAdd(&cnt[r.w], 1);
    u64 p0 = ((u64)r.x << 33) | ((u64)(unsigned)c.x << 16) | f2bf(v.x);
    u64 p1 = ((u64)r.y << 33) | ((u64)(unsigned)c.y << 16) | f2bf(v.y);
    u64 p2 = ((u64)r.z << 33) | ((u64)(unsigned)c.z << 16) | f2bf(v.z);
    u64 p3 = ((u64)r.w << 33) | ((u64)(unsigned)c.w << 16) | f2bf(v.w);
    u64* dst = pe + (long)i * 4;
    dst[0] = p0; dst[1] = p1; dst[2] = p2; dst[3] = p3;
}

// ---------------- scans (rp = exclusive scan of cnt) ----------------
__global__ void k_scan1(const int* __restrict__ cnt, int* __restrict__ rp, int* __restrict__ bsum) {
    __shared__ int sm[256];
    int i = blockIdx.x * 256 + threadIdx.x;
    int v = (i < NTOT) ? cnt[i] : 0;
    sm[threadIdx.x] = v;
    __syncthreads();
    for (int off = 1; off < 256; off <<= 1) {
        int t = (threadIdx.x >= off) ? sm[threadIdx.x - off] : 0;
        __syncthreads();
        sm[threadIdx.x] += t;
        __syncthreads();
    }
    if (i < NTOT) rp[i] = sm[threadIdx.x] - v;
    if (threadIdx.x == 255) bsum[blockIdx.x] = sm[255];
}

__global__ void k_scan2(int* bsum, int nb) {
    __shared__ int sm[512];
    int v = (threadIdx.x < nb) ? bsum[threadIdx.x] : 0;
    sm[threadIdx.x] = v;
    __syncthreads();
    for (int off = 1; off < 512; off <<= 1) {
        int t = (threadIdx.x >= off) ? sm[threadIdx.x - off] : 0;
        __syncthreads();
        sm[threadIdx.x] += t;
        __syncthreads();
    }
    if (threadIdx.x < nb) bsum[threadIdx.x] = sm[threadIdx.x] - v;
}

// finalize rp; also init bucket cursors gbcur[b] = rp[b*512]
__global__ void k_scan3(int* __restrict__ rp, const int* __restrict__ bsum, int* __restrict__ gbcur) {
    int i = blockIdx.x * 256 + threadIdx.x;
    if (i < NTOT) {
        int v = rp[i] + bsum[blockIdx.x];
        rp[i] = v;
        if ((i & 511) == 0) gbcur[i >> 9] = v;
    }
    if (i == 0) rp[NTOT] = NNZC;
}

// ---------------- bucket partition: block-bulk reservation ----------------
__global__ __launch_bounds__(256) void k_scatterB(const u64* __restrict__ pe, int* __restrict__ gbcur,
                                                  u64* __restrict__ eb) {
    __shared__ int bh[NBKT], bbase[NBKT], bcur[NBKT];
    int tid = threadIdx.x;
    for (int i = tid; i < NBKT; i += 256) { bh[i] = 0; bcur[i] = 0; }
    __syncthreads();
    long base = (long)blockIdx.x * 4096;
    u64 e[16]; int bk[16];
    #pragma unroll
    for (int i = 0; i < 16; i++) {
        long idx = base + i * 256 + tid;
        if (idx < NNZC) {
            e[i] = pe[idx];
            bk[i] = (int)(e[i] >> 42);      // row >> 9
            atomicAdd(&bh[bk[i]], 1);
        } else bk[i] = -1;
    }
    __syncthreads();
    for (int i = tid; i < NBKT; i += 256)
        if (bh[i] > 0) bbase[i] = atomicAdd(&gbcur[i], bh[i]);
    __syncthreads();
    #pragma unroll
    for (int i = 0; i < 16; i++) {
        if (bk[i] >= 0) {
            int p = bbase[bk[i]] + atomicAdd(&bcur[bk[i]], 1);
            eb[p] = e[i];
        }
    }
}

// ---------------- bucket -> row-CSR: one block per bucket, LDS row cursors ----------------
__global__ __launch_bounds__(256) void k_csrC(const u64* __restrict__ eb, const int* __restrict__ rp,
                                              u64* __restrict__ ecv) {
    __shared__ int lcur[512];
    int b = blockIdx.x;
    int row0 = b << 9;
    for (int i = threadIdx.x; i < 512; i += 256) {
        int rg = row0 + i;
        if (rg < NTOT) lcur[i] = rp[rg];
    }
    __syncthreads();
    int start = rp[row0];
    int end = (row0 + 512 <= NTOT) ? rp[row0 + 512] : NNZC;
    for (int e = start + threadIdx.x; e < end; e += 256) {
        u64 w = eb[e];
        int row = (int)(w >> 33);
        int rl = row - row0;
        u64 col = (w >> 16) & 0x1FFFF;
        u64 vbf = w & 0xFFFF;
        int p = atomicAdd(&lcur[rl], 1);
        ecv[p] = (vbf << 48) | col;   // high16 of high32 = bf16 val, low32 = col
    }
}

// ---------------- SpMM: one wave per row, 4 edges/step (16 lanes per edge) ----------------
__global__ __launch_bounds__(256) void k_spmm(const int* __restrict__ rp, const long* __restrict__ ecv,
                                              const unsigned short* __restrict__ xb,
                                              unsigned short* __restrict__ side_bf) {
    int r = (blockIdx.x * blockDim.x + threadIdx.x) >> 6;
    int lane = threadIdx.x & 63;
    if (r >= NTOT) return;
    int q = lane >> 4;
    int t4 = (lane & 15) * 4;
    int s = rp[r], e = rp[r + 1];
    float a0 = 0.f, a1 = 0.f, a2 = 0.f, a3 = 0.f;
    for (int j = s; j < e; j += 16) {
        long pk[4];
        bool vm[4];
        #pragma unroll
        for (int u = 0; u < 4; ++u) {
            int je = j + u * 4 + q;
            vm[u] = (je < e);
            pk[u] = __builtin_nontemporal_load(ecv + (vm[u] ? je : 0));
        }
        ushort4 xv[4];
        #pragma unroll
        for (int u = 0; u < 4; ++u)
            xv[u] = *(const ushort4*)(xb + (long)(int)pk[u] * EMBC + t4);
        #pragma unroll
        for (int u = 0; u < 4; ++u) {
            float w = vm[u] ? __int_as_float((int)(pk[u] >> 32)) : 0.f;
            a0 += w * bf2f(xv[u].x);
            a1 += w * bf2f(xv[u].y);
            a2 += w * bf2f(xv[u].z);
            a3 += w * bf2f(xv[u].w);
        }
    }
    a0 += __shfl_xor(a0, 16); a1 += __shfl_xor(a1, 16); a2 += __shfl_xor(a2, 16); a3 += __shfl_xor(a3, 16);
    a0 += __shfl_xor(a0, 32); a1 += __shfl_xor(a1, 32); a2 += __shfl_xor(a2, 32); a3 += __shfl_xor(a3, 32);
    if (lane < 16) {
        ushort4 o; o.x = f2bf(a0); o.y = f2bf(a1); o.z = f2bf(a2); o.w = f2bf(a3);
        *(ushort4*)(side_bf + (long)r * EMBC + t4) = o;
    }
}

// ------------- MFMA layer: [sum_emb + bi_emb + bias] -> leaky_relu, updates xb (bf16 state) -------------
#define RPB 128
#define LDP 72
__global__ __launch_bounds__(256) void k_layer_mfma(
    const unsigned short* __restrict__ side_bf, unsigned short* __restrict__ xb,
    const float* __restrict__ Wgc, const float* __restrict__ bgc,
    const float* __restrict__ Wbi, const float* __restrict__ bbi)
{
    __shared__ unsigned short sS[RPB * LDP];
    __shared__ unsigned short sM[RPB * LDP];
    __shared__ unsigned short sWg[64 * LDP];
    __shared__ unsigned short sWb[64 * LDP];
    __shared__ float sBias[64];

    int tid = threadIdx.x;
    int row0 = blockIdx.x * RPB;

    for (int i = tid; i < 4096; i += 256) {
        int d = i >> 6, c = i & 63;
        sWg[c * LDP + d] = f2bf(Wgc[i]);
        sWb[c * LDP + d] = f2bf(Wbi[i]);
    }
    if (tid < 64) sBias[tid] = bgc[tid] + bbi[tid];

    #pragma unroll
    for (int it = 0; it < (RPB * 8) / 256; ++it) {
        int item = it * 256 + tid;
        int r = item >> 3, ch = item & 7;
        long grow = row0 + r;
        uint4 sv = make_uint4(0, 0, 0, 0), ev = make_uint4(0, 0, 0, 0);
        if (grow < NTOT) {
            sv = *(const uint4*)(side_bf + grow * 64 + ch * 8);
            ev = *(const uint4*)(xb + grow * 64 + ch * 8);
        }
        uint4 mv;
        mv.x = f2bf(bf2f(ev.x & 0xffff) * bf2f(sv.x & 0xffff)) |
               ((unsigned int)f2bf(bf2f(ev.x >> 16) * bf2f(sv.x >> 16)) << 16);
        mv.y = f2bf(bf2f(ev.y & 0xffff) * bf2f(sv.y & 0xffff)) |
               ((unsigned int)f2bf(bf2f(ev.y >> 16) * bf2f(sv.y >> 16)) << 16);
        mv.z = f2bf(bf2f(ev.z & 0xffff) * bf2f(sv.z & 0xffff)) |
               ((unsigned int)f2bf(bf2f(ev.z >> 16) * bf2f(sv.z >> 16)) << 16);
        mv.w = f2bf(bf2f(ev.w & 0xffff) * bf2f(sv.w & 0xffff)) |
               ((unsigned int)f2bf(bf2f(ev.w >> 16) * bf2f(sv.w >> 16)) << 16);
        *(uint4*)(sS + r * LDP + ch * 8) = sv;
        *(uint4*)(sM + r * LDP + ch * 8) = mv;
    }
    __syncthreads();

    int wave = tid >> 6, lane = tid & 63;
    int quad = lane >> 4, l16 = lane & 15;

    floatx4 accG[2][4], accB[2][4];
    #pragma unroll
    for (int rt = 0; rt < 2; rt++)
        #pragma unroll
        for (int ct = 0; ct < 4; ct++) {
            accG[rt][ct] = (floatx4){0.f, 0.f, 0.f, 0.f};
            accB[rt][ct] = (floatx4){0.f, 0.f, 0.f, 0.f};
        }

    #pragma unroll
    for (int kc = 0; kc < 64; kc += 32) {
        shortx8 aS[2], aM[2];
        #pragma unroll
        for (int rt = 0; rt < 2; rt++) {
            int r = wave * 32 + rt * 16 + l16;
            aS[rt] = *(const shortx8*)(sS + r * LDP + kc + quad * 8);
            aM[rt] = *(const shortx8*)(sM + r * LDP + kc + quad * 8);
        }
        #pragma unroll
        for (int ct = 0; ct < 4; ct++) {
            int c = ct * 16 + l16;
            shortx8 bG = *(const shortx8*)(sWg + c * LDP + kc + quad * 8);
            shortx8 bB = *(const shortx8*)(sWb + c * LDP + kc + quad * 8);
            #pragma unroll
            for (int rt = 0; rt < 2; rt++) {
                accG[rt][ct] = __builtin_amdgcn_mfma_f32_16x16x32_bf16(aS[rt], bG, accG[rt][ct], 0, 0, 0);
                accB[rt][ct] = __builtin_amdgcn_mfma_f32_16x16x32_bf16(aM[rt], bB, accB[rt][ct], 0, 0, 0);
            }
        }
    }

    #pragma unroll
    for (int rt = 0; rt < 2; rt++)
        #pragma unroll
        for (int ct = 0; ct < 4; ct++) {
            int c = ct * 16 + l16;
            float bs = sBias[c];
            #pragma unroll
            for (int reg = 0; reg < 4; reg++) {
                int r = wave * 32 + rt * 16 + quad * 4 + reg;
                long grow = row0 + r;
                if (grow < NTOT) {
                    float v = accG[rt][ct][reg] + accB[rt][ct][reg] + bs;
                    float o = (v > 0.f) ? v : 0.2f * v;
                    xb[grow * 64 + c] = f2bf(o);
                }
            }
        }
}

// ------------- gather batch rows (optionally L2-normalized) into d_out -------------
__global__ __launch_bounds__(256) void k_gather(const unsigned short* __restrict__ xb,
                                                const int* __restrict__ users,
                                                const int* __restrict__ pos,
                                                const int* __restrict__ neg,
                                                float* __restrict__ out, int colOff, int normalize) {
    int slot = (blockIdx.x * blockDim.x + threadIdx.x) >> 6;
    int lane = threadIdx.x & 63;
    if (slot >= NSLOT) return;
    int row;
    if (slot < BATCHC)          row = users[slot];
    else if (slot < 2 * BATCHC) row = N_USERC + pos[slot - BATCHC];
    else                        row = N_USERC + neg[slot - 2 * BATCHC];
    float v = bf2f(xb[(long)row * 64 + lane]);
    if (normalize) {
        float ss = v * v;
        for (int off = 32; off > 0; off >>= 1) ss += __shfl_xor(ss, off);
        float nrm = fmaxf(sqrtf(ss), 1e-12f);
        v = v / nrm;
    }
    out[(long)slot * 256 + colOff + lane] = v;
}

extern "C" void kernel_launch(void* const* d_in, const int* in_sizes, int n_in,
                              void* d_out, int out_size, void* d_ws, size_t ws_size,
                              hipStream_t stream) {
    const int*   users   = (const int*)d_in[0];
    const int*   pos     = (const int*)d_in[1];
    const int*   neg     = (const int*)d_in[2];
    const int*   adj_row = (const int*)d_in[3];
    const int*   adj_col = (const int*)d_in[4];
    const float* adj_val = (const float*)d_in[5];
    const float* user_emb = (const float*)d_in[6];
    const float* item_emb = (const float*)d_in[7];
    const float* W_gc = (const float*)d_in[8];
    const float* b_gc = (const float*)d_in[9];
    const float* W_bi = (const float*)d_in[10];
    const float* b_bi = (const float*)d_in[11];
    float* out = (float*)d_out;

    // workspace carve-up (~78 MB); ecv aliases pe (pe dead after k_scatterB)
    char* p = (char*)d_ws;
    u64*  pe  = (u64*)p;                        p += (size_t)NNZC * 8;   // packed edges / final CSR
    u64*  ecv = pe;
    u64*  eb  = (u64*)p;                        p += (size_t)NNZC * 8;   // bucket-grouped edges
    unsigned short* side_bf = (unsigned short*)p; p += (size_t)NTOT * EMBC * 2;
    unsigned short* xb = (unsigned short*)p;    p += (size_t)NTOT * EMBC * 2;
    int*  cnt = (int*)p;                        p += (size_t)NTOT * 4;
    int*  rp  = (int*)p;                        p += (size_t)(NTOT + 1) * 4 + 60;
    int*  gbcur = (int*)p;                      p += 1024;
    int*  bsum = (int*)p;                       p += 2048;

    const int NB_SCAN = (NTOT + 255) / 256;   // 391

    k_init_xb<<<(NTOT * EMBC / 4 + 255) / 256, 256, 0, stream>>>(
        (const float4*)user_emb, (const float4*)item_emb, (ushort4*)xb);

    k_zero_cnt<<<NB_SCAN, 256, 0, stream>>>(cnt);
    k_pack_hist<<<(NNZC / 4 + 255) / 256, 256, 0, stream>>>(
        (const intx4*)adj_row, (const intx4*)adj_col, (const floatx4*)adj_val, cnt, pe);
    k_scan1<<<NB_SCAN, 256, 0, stream>>>(cnt, rp, bsum);
    k_scan2<<<1, 512, 0, stream>>>(bsum, NB_SCAN);
    k_scan3<<<NB_SCAN, 256, 0, stream>>>(rp, bsum, gbcur);
    k_scatterB<<<(NNZC + 4095) / 4096, 256, 0, stream>>>(pe, gbcur, eb);
    k_csrC<<<NBKT, 256, 0, stream>>>(eb, rp, ecv);

    // layer-0 slice of all_embs = raw ego (no normalization)
    k_gather<<<(NSLOT * 64 + 255) / 256, 256, 0, stream>>>(xb, users, pos, neg, out, 0, 0);

    const int NB_LAYER = (NTOT + RPB - 1) / RPB;
    for (int k = 0; k < 3; k++) {
        k_spmm<<<NTOT / 4, 256, 0, stream>>>(rp, (const long*)ecv, xb, side_bf);
        k_layer_mfma<<<NB_LAYER, 256, 0, stream>>>(side_bf, xb,
            W_gc + (size_t)k * 4096, b_gc + (size_t)k * 64,
            W_bi + (size_t)k * 4096, b_bi + (size_t)k * 64);
        k_gather<<<(NSLOT * 64 + 255) / 256, 256, 0, stream>>>(xb, users, pos, neg, out, 64 * (k + 1), 1);
    }
}

// Round 8
// 548.371 us; speedup vs baseline: 2.8766x; 1.0961x over previous
//
#include <hip/hip_runtime.h>
#include <hip/hip_bf16.h>

#define N_USERC 50000
#define N_ITEMC 50000
#define NTOT    100000
#define NNZC    3200000
#define EMBC    64
#define BATCHC  4096
#define NSLOT   (3*BATCHC)
#define NBKT    196            // buckets of 512 rows
typedef unsigned long long u64;

typedef __attribute__((ext_vector_type(4))) float floatx4;
typedef __attribute__((ext_vector_type(4))) int   intx4;
typedef __attribute__((ext_vector_type(8))) short shortx8;   // 8 bf16 = 4 VGPRs

__device__ __forceinline__ float bf2f(unsigned short u) {
    return __int_as_float(((int)u) << 16);
}
__device__ __forceinline__ unsigned short f2bf(float f) {
    __hip_bfloat16 h = __float2bfloat16(f);      // RTNE
    return *(unsigned short*)&h;
}

// ---------------- init: xb = bf16(concat(user_emb, item_emb)) ----------------
__global__ void k_init_xb(const float4* __restrict__ ue, const float4* __restrict__ ie,
                          ushort4* __restrict__ xb) {
    long i = (long)blockIdx.x * blockDim.x + threadIdx.x;
    const long nu4 = (long)N_USERC * EMBC / 4;
    const long tot4 = (long)NTOT * EMBC / 4;
    if (i < tot4) {
        float4 v = (i < nu4) ? ue[i] : ie[i - nu4];
        ushort4 b; b.x = f2bf(v.x); b.y = f2bf(v.y); b.z = f2bf(v.z); b.w = f2bf(v.w);
        xb[i] = b;
    }
}

__global__ void k_zero_bcnt(int* bcnt) {
    if (threadIdx.x < NBKT + 1) bcnt[threadIdx.x] = 0;
}

// ---------------- pack edges to 8B (row|col|bf16val) + LDS bucket histogram ----------------
__global__ __launch_bounds__(256) void k_packB(const intx4* __restrict__ row4, const intx4* __restrict__ col4,
                                               const floatx4* __restrict__ val4, int* __restrict__ bcnt,
                                               u64* __restrict__ pe) {
    __shared__ int bh[NBKT];
    int tid = threadIdx.x;
    for (int i = tid; i < NBKT; i += 256) bh[i] = 0;
    __syncthreads();
    int i = blockIdx.x * 256 + tid;          // group of 4 edges
    if (i < NNZC / 4) {
        intx4 r = __builtin_nontemporal_load(row4 + i);
        intx4 c = __builtin_nontemporal_load(col4 + i);
        floatx4 v = __builtin_nontemporal_load(val4 + i);
        atomicAdd(&bh[r.x >> 9], 1);
        atomicAdd(&bh[r.y >> 9], 1);
        atomicAdd(&bh[r.z >> 9], 1);
        atomicAdd(&bh[r.w >> 9], 1);
        u64 p0 = ((u64)r.x << 33) | ((u64)(unsigned)c.x << 16) | f2bf(v.x);
        u64 p1 = ((u64)r.y << 33) | ((u64)(unsigned)c.y << 16) | f2bf(v.y);
        u64 p2 = ((u64)r.z << 33) | ((u64)(unsigned)c.z << 16) | f2bf(v.z);
        u64 p3 = ((u64)r.w << 33) | ((u64)(unsigned)c.w << 16) | f2bf(v.w);
        u64* dst = pe + (long)i * 4;
        dst[0] = p0; dst[1] = p1; dst[2] = p2; dst[3] = p3;
    }
    __syncthreads();
    for (int b = tid; b < NBKT; b += 256)
        if (bh[b] > 0) atomicAdd(&bcnt[b], bh[b]);
}

// ---------------- scan 196 bucket counts -> bases; init cursors ----------------
__global__ void k_bktscan(const int* __restrict__ bcnt, int* __restrict__ bbase0,
                          int* __restrict__ gbcur) {
    __shared__ int sm[256];
    int t = threadIdx.x;
    int v = (t < NBKT) ? bcnt[t] : 0;
    sm[t] = v;
    __syncthreads();
    for (int off = 1; off < 256; off <<= 1) {
        int u = (t >= off) ? sm[t - off] : 0;
        __syncthreads();
        sm[t] += u;
        __syncthreads();
    }
    if (t < NBKT) {
        int base = sm[t] - v;   // exclusive
        bbase0[t] = base;
        gbcur[t] = base;
    }
    if (t == 0) bbase0[NBKT] = NNZC;
}

// ---------------- bucket partition: block-bulk reservation ----------------
__global__ __launch_bounds__(256) void k_scatterB(const u64* __restrict__ pe, int* __restrict__ gbcur,
                                                  u64* __restrict__ eb) {
    __shared__ int bh[NBKT], bbase[NBKT], bcur[NBKT];
    int tid = threadIdx.x;
    for (int i = tid; i < NBKT; i += 256) { bh[i] = 0; bcur[i] = 0; }
    __syncthreads();
    long base = (long)blockIdx.x * 4096;
    u64 e[16]; int bk[16];
    #pragma unroll
    for (int i = 0; i < 16; i++) {
        long idx = base + i * 256 + tid;
        if (idx < NNZC) {
            e[i] = __builtin_nontemporal_load(pe + idx);
            bk[i] = (int)(e[i] >> 42);      // row >> 9
            atomicAdd(&bh[bk[i]], 1);
        } else bk[i] = -1;
    }
    __syncthreads();
    for (int i = tid; i < NBKT; i += 256)
        if (bh[i] > 0) bbase[i] = atomicAdd(&gbcur[i], bh[i]);
    __syncthreads();
    #pragma unroll
    for (int i = 0; i < 16; i++) {
        if (bk[i] >= 0) {
            int p = bbase[bk[i]] + atomicAdd(&bcur[bk[i]], 1);
            eb[p] = e[i];
        }
    }
}

// ---------------- bucket -> row-CSR + rp build: one block per bucket ----------------
__global__ __launch_bounds__(256) void k_csrC(const u64* __restrict__ eb, const int* __restrict__ bbase0,
                                              int* __restrict__ rp, u64* __restrict__ ecv) {
    __shared__ int lhist[512];
    __shared__ int lcur[512];
    __shared__ int sm[256];
    int b = blockIdx.x;
    int tid = threadIdx.x;
    int row0 = b << 9;
    lhist[tid] = 0; lhist[tid + 256] = 0;
    __syncthreads();
    int start = bbase0[b];
    int end = bbase0[b + 1];
    // pass 1: histogram rows within bucket
    for (int e = start + tid; e < end; e += 256) {
        u64 w = eb[e];
        int rl = (int)(w >> 33) - row0;
        atomicAdd(&lhist[rl], 1);
    }
    __syncthreads();
    // scan 512 with 256 threads (2 consecutive elems per thread)
    int h0 = lhist[2 * tid], h1 = lhist[2 * tid + 1];
    int pair = h0 + h1;
    sm[tid] = pair;
    __syncthreads();
    for (int off = 1; off < 256; off <<= 1) {
        int u = (tid >= off) ? sm[tid - off] : 0;
        __syncthreads();
        sm[tid] += u;
        __syncthreads();
    }
    int pairExcl = sm[tid] - pair;
    int e0 = start + pairExcl;
    int e1 = e0 + h0;
    lcur[2 * tid] = e0;
    lcur[2 * tid + 1] = e1;
    // write rp
    int rg0 = row0 + 2 * tid, rg1 = rg0 + 1;
    if (rg0 < NTOT) rp[rg0] = e0;
    if (rg1 < NTOT) rp[rg1] = e1;
    if (b == NBKT - 1 && tid == 0) rp[NTOT] = NNZC;
    __syncthreads();
    // pass 2: place edges
    for (int e = start + tid; e < end; e += 256) {
        u64 w = eb[e];
        int rl = (int)(w >> 33) - row0;
        u64 col = (w >> 16) & 0x1FFFF;
        u64 vbf = w & 0xFFFF;
        int p = atomicAdd(&lcur[rl], 1);
        ecv[p] = (vbf << 48) | col;   // high32 = f32 bits of bf16 val, low32 = col
    }
}

// ---------------- SpMM: one wave per row, 4 edges/step (16 lanes per edge) ----------------
__global__ __launch_bounds__(256) void k_spmm(const int* __restrict__ rp, const long* __restrict__ ecv,
                                              const unsigned short* __restrict__ xb,
                                              unsigned short* __restrict__ side_bf) {
    int r = (blockIdx.x * blockDim.x + threadIdx.x) >> 6;
    int lane = threadIdx.x & 63;
    if (r >= NTOT) return;
    int q = lane >> 4;
    int t4 = (lane & 15) * 4;
    int s = rp[r], e = rp[r + 1];
    float a0 = 0.f, a1 = 0.f, a2 = 0.f, a3 = 0.f;
    for (int j = s; j < e; j += 16) {
        long pk[4];
        bool vm[4];
        #pragma unroll
        for (int u = 0; u < 4; ++u) {
            int je = j + u * 4 + q;
            vm[u] = (je < e);
            pk[u] = __builtin_nontemporal_load(ecv + (vm[u] ? je : 0));
        }
        ushort4 xv[4];
        #pragma unroll
        for (int u = 0; u < 4; ++u)
            xv[u] = *(const ushort4*)(xb + (long)(int)pk[u] * EMBC + t4);
        #pragma unroll
        for (int u = 0; u < 4; ++u) {
            float w = vm[u] ? __int_as_float((int)(pk[u] >> 32)) : 0.f;
            a0 += w * bf2f(xv[u].x);
            a1 += w * bf2f(xv[u].y);
            a2 += w * bf2f(xv[u].z);
            a3 += w * bf2f(xv[u].w);
        }
    }
    a0 += __shfl_xor(a0, 16); a1 += __shfl_xor(a1, 16); a2 += __shfl_xor(a2, 16); a3 += __shfl_xor(a3, 16);
    a0 += __shfl_xor(a0, 32); a1 += __shfl_xor(a1, 32); a2 += __shfl_xor(a2, 32); a3 += __shfl_xor(a3, 32);
    if (lane < 16) {
        ushort4 o; o.x = f2bf(a0); o.y = f2bf(a1); o.z = f2bf(a2); o.w = f2bf(a3);
        *(ushort4*)(side_bf + (long)r * EMBC + t4) = o;
    }
}

// ------------- MFMA layer: [sum_emb + bi_emb + bias] -> leaky_relu, updates xb (bf16 state) -------------
#define RPB 128
#define LDP 72
__global__ __launch_bounds__(256) void k_layer_mfma(
    const unsigned short* __restrict__ side_bf, unsigned short* __restrict__ xb,
    const float* __restrict__ Wgc, const float* __restrict__ bgc,
    const float* __restrict__ Wbi, const float* __restrict__ bbi)
{
    __shared__ unsigned short sS[RPB * LDP];
    __shared__ unsigned short sM[RPB * LDP];
    __shared__ unsigned short sWg[64 * LDP];
    __shared__ unsigned short sWb[64 * LDP];
    __shared__ float sBias[64];

    int tid = threadIdx.x;
    int row0 = blockIdx.x * RPB;

    for (int i = tid; i < 4096; i += 256) {
        int d = i >> 6, c = i & 63;
        sWg[c * LDP + d] = f2bf(Wgc[i]);
        sWb[c * LDP + d] = f2bf(Wbi[i]);
    }
    if (tid < 64) sBias[tid] = bgc[tid] + bbi[tid];

    #pragma unroll
    for (int it = 0; it < (RPB * 8) / 256; ++it) {
        int item = it * 256 + tid;
        int r = item >> 3, ch = item & 7;
        long grow = row0 + r;
        uint4 sv = make_uint4(0, 0, 0, 0), ev = make_uint4(0, 0, 0, 0);
        if (grow < NTOT) {
            sv = *(const uint4*)(side_bf + grow * 64 + ch * 8);
            ev = *(const uint4*)(xb + grow * 64 + ch * 8);
        }
        uint4 mv;
        mv.x = f2bf(bf2f(ev.x & 0xffff) * bf2f(sv.x & 0xffff)) |
               ((unsigned int)f2bf(bf2f(ev.x >> 16) * bf2f(sv.x >> 16)) << 16);
        mv.y = f2bf(bf2f(ev.y & 0xffff) * bf2f(sv.y & 0xffff)) |
               ((unsigned int)f2bf(bf2f(ev.y >> 16) * bf2f(sv.y >> 16)) << 16);
        mv.z = f2bf(bf2f(ev.z & 0xffff) * bf2f(sv.z & 0xffff)) |
               ((unsigned int)f2bf(bf2f(ev.z >> 16) * bf2f(sv.z >> 16)) << 16);
        mv.w = f2bf(bf2f(ev.w & 0xffff) * bf2f(sv.w & 0xffff)) |
               ((unsigned int)f2bf(bf2f(ev.w >> 16) * bf2f(sv.w >> 16)) << 16);
        *(uint4*)(sS + r * LDP + ch * 8) = sv;
        *(uint4*)(sM + r * LDP + ch * 8) = mv;
    }
    __syncthreads();

    int wave = tid >> 6, lane = tid & 63;
    int quad = lane >> 4, l16 = lane & 15;

    floatx4 accG[2][4], accB[2][4];
    #pragma unroll
    for (int rt = 0; rt < 2; rt++)
        #pragma unroll
        for (int ct = 0; ct < 4; ct++) {
            accG[rt][ct] = (floatx4){0.f, 0.f, 0.f, 0.f};
            accB[rt][ct] = (floatx4){0.f, 0.f, 0.f, 0.f};
        }

    #pragma unroll
    for (int kc = 0; kc < 64; kc += 32) {
        shortx8 aS[2], aM[2];
        #pragma unroll
        for (int rt = 0; rt < 2; rt++) {
            int r = wave * 32 + rt * 16 + l16;
            aS[rt] = *(const shortx8*)(sS + r * LDP + kc + quad * 8);
            aM[rt] = *(const shortx8*)(sM + r * LDP + kc + quad * 8);
        }
        #pragma unroll
        for (int ct = 0; ct < 4; ct++) {
            int c = ct * 16 + l16;
            shortx8 bG = *(const shortx8*)(sWg + c * LDP + kc + quad * 8);
            shortx8 bB = *(const shortx8*)(sWb + c * LDP + kc + quad * 8);
            #pragma unroll
            for (int rt = 0; rt < 2; rt++) {
                accG[rt][ct] = __builtin_amdgcn_mfma_f32_16x16x32_bf16(aS[rt], bG, accG[rt][ct], 0, 0, 0);
                accB[rt][ct] = __builtin_amdgcn_mfma_f32_16x16x32_bf16(aM[rt], bB, accB[rt][ct], 0, 0, 0);
            }
        }
    }

    #pragma unroll
    for (int rt = 0; rt < 2; rt++)
        #pragma unroll
        for (int ct = 0; ct < 4; ct++) {
            int c = ct * 16 + l16;
            float bs = sBias[c];
            #pragma unroll
            for (int reg = 0; reg < 4; reg++) {
                int r = wave * 32 + rt * 16 + quad * 4 + reg;
                long grow = row0 + r;
                if (grow < NTOT) {
                    float v = accG[rt][ct][reg] + accB[rt][ct][reg] + bs;
                    float o = (v > 0.f) ? v : 0.2f * v;
                    xb[grow * 64 + c] = f2bf(o);
                }
            }
        }
}

// ------------- gather batch rows (optionally L2-normalized) into d_out -------------
__global__ __launch_bounds__(256) void k_gather(const unsigned short* __restrict__ xb,
                                                const int* __restrict__ users,
                                                const int* __restrict__ pos,
                                                const int* __restrict__ neg,
                                                float* __restrict__ out, int colOff, int normalize) {
    int slot = (blockIdx.x * blockDim.x + threadIdx.x) >> 6;
    int lane = threadIdx.x & 63;
    if (slot >= NSLOT) return;
    int row;
    if (slot < BATCHC)          row = users[slot];
    else if (slot < 2 * BATCHC) row = N_USERC + pos[slot - BATCHC];
    else                        row = N_USERC + neg[slot - 2 * BATCHC];
    float v = bf2f(xb[(long)row * 64 + lane]);
    if (normalize) {
        float ss = v * v;
        for (int off = 32; off > 0; off >>= 1) ss += __shfl_xor(ss, off);
        float nrm = fmaxf(sqrtf(ss), 1e-12f);
        v = v / nrm;
    }
    out[(long)slot * 256 + colOff + lane] = v;
}

extern "C" void kernel_launch(void* const* d_in, const int* in_sizes, int n_in,
                              void* d_out, int out_size, void* d_ws, size_t ws_size,
                              hipStream_t stream) {
    const int*   users   = (const int*)d_in[0];
    const int*   pos     = (const int*)d_in[1];
    const int*   neg     = (const int*)d_in[2];
    const int*   adj_row = (const int*)d_in[3];
    const int*   adj_col = (const int*)d_in[4];
    const float* adj_val = (const float*)d_in[5];
    const float* user_emb = (const float*)d_in[6];
    const float* item_emb = (const float*)d_in[7];
    const float* W_gc = (const float*)d_in[8];
    const float* b_gc = (const float*)d_in[9];
    const float* W_bi = (const float*)d_in[10];
    const float* b_bi = (const float*)d_in[11];
    float* out = (float*)d_out;

    // workspace carve-up (~78 MB); ecv aliases pe (pe dead after k_scatterB)
    char* p = (char*)d_ws;
    u64*  pe  = (u64*)p;                        p += (size_t)NNZC * 8;   // packed edges / final CSR
    u64*  ecv = pe;
    u64*  eb  = (u64*)p;                        p += (size_t)NNZC * 8;   // bucket-grouped edges
    unsigned short* side_bf = (unsigned short*)p; p += (size_t)NTOT * EMBC * 2;
    unsigned short* xb = (unsigned short*)p;    p += (size_t)NTOT * EMBC * 2;
    int*  rp  = (int*)p;                        p += (size_t)(NTOT + 1) * 4 + 60;
    int*  bcnt = (int*)p;                       p += 1024;
    int*  bbase0 = (int*)p;                     p += 1024;
    int*  gbcur = (int*)p;                      p += 1024;

    k_init_xb<<<(NTOT * EMBC / 4 + 255) / 256, 256, 0, stream>>>(
        (const float4*)user_emb, (const float4*)item_emb, (ushort4*)xb);

    k_zero_bcnt<<<1, 256, 0, stream>>>(bcnt);
    k_packB<<<(NNZC / 4 + 255) / 256, 256, 0, stream>>>(
        (const intx4*)adj_row, (const intx4*)adj_col, (const floatx4*)adj_val, bcnt, pe);
    k_bktscan<<<1, 256, 0, stream>>>(bcnt, bbase0, gbcur);
    k_scatterB<<<(NNZC + 4095) / 4096, 256, 0, stream>>>(pe, gbcur, eb);
    k_csrC<<<NBKT, 256, 0, stream>>>(eb, bbase0, rp, ecv);

    // layer-0 slice of all_embs = raw ego (no normalization)
    k_gather<<<(NSLOT * 64 + 255) / 256, 256, 0, stream>>>(xb, users, pos, neg, out, 0, 0);

    const int NB_LAYER = (NTOT + RPB - 1) / RPB;
    for (int k = 0; k < 3; k++) {
        k_spmm<<<NTOT / 4, 256, 0, stream>>>(rp, (const long*)ecv, xb, side_bf);
        k_layer_mfma<<<NB_LAYER, 256, 0, stream>>>(side_bf, xb,
            W_gc + (size_t)k * 4096, b_gc + (size_t)k * 64,
            W_bi + (size_t)k * 4096, b_bi + (size_t)k * 64);
        k_gather<<<(NSLOT * 64 + 255) / 256, 256, 0, stream>>>(xb, users, pos, neg, out, 64 * (k + 1), 1);
    }
}